// Round 12
// baseline (228.525 us; speedup 1.0000x reference)
//
#include <hip/hip_runtime.h>
#include <math.h>

static constexpr int BB = 2;
static constexpr int TT = 1024;
static constexpr int CC = 2048;
static constexpr int HH = 32;
static constexpr int KD = 64;
static constexpr int BT = BB * TT;

typedef short   v8s  __attribute__((ext_vector_type(8)));
typedef float   v4f  __attribute__((ext_vector_type(4)));
typedef unsigned short u16;
typedef u16     u16x8 __attribute__((ext_vector_type(8)));
typedef u16     u16x4 __attribute__((ext_vector_type(4)));
typedef float   fx4  __attribute__((ext_vector_type(4)));

__device__ __forceinline__ u16 f2bf(float f) {
    unsigned u = __builtin_bit_cast(unsigned, f);
    u = u + 0x7FFFu + ((u >> 16) & 1u);   // RNE
    return (u16)(u >> 16);
}
__device__ __forceinline__ float bf2f(u16 v) {
    return __builtin_bit_cast(float, ((unsigned)v) << 16);
}

// async global->LDS, 16B per lane; dest is wave-uniform base + lane*16
__device__ __forceinline__ void gld16(const u16* g, u16* l) {
    __builtin_amdgcn_global_load_lds(
        (const __attribute__((address_space(1))) void*)g,
        (__attribute__((address_space(3))) void*)l, 16, 0, 0);
}

__device__ __forceinline__ void cstore(float* p, float v) { *p = v; }
__device__ __forceinline__ void cstore(u16* p, float v)   { *p = f2bf(v); }

// XCD chunk swizzle: 256 blocks -> 16x16 tile grid, each XCD a 4x8 chunk
__device__ __forceinline__ void xcd_map(int bid, int& bx, int& by) {
    int i = bid & 7;
    int j = bid >> 3;
    bx = (i & 3) * 4 + (j & 3);
    by = (i >> 2) * 8 + (j >> 2);
}

// ---------------- transpose-convert weights (z<4) + w1 (z==4) ----------------
__global__ __launch_bounds__(256) void k_tconv5(const float* __restrict__ W0,
                                                const float* __restrict__ W1,
                                                const float* __restrict__ W2,
                                                const float* __restrict__ W3,
                                                const float* __restrict__ w1,
                                                u16* __restrict__ T0, u16* __restrict__ T1,
                                                u16* __restrict__ T2, u16* __restrict__ T3,
                                                u16* __restrict__ w1t) {
    __shared__ float tile[64][97];
    int tid = threadIdx.x;
    int z = blockIdx.z;
    if (z == 4) {                              // w1 f32 [2048][96] -> bf16 [96][2048]
        if (blockIdx.y != 0) return;
        int kb = blockIdx.x * 64;
        for (int i = tid; i < 64 * 96; i += 256) {
            int r = i / 96, c = i - r * 96;
            tile[r][c] = w1[(size_t)(kb + r) * 96 + c];
        }
        __syncthreads();
        for (int i = tid; i < 96 * 64; i += 256) {
            int n = i >> 6, k = i & 63;
            w1t[(size_t)n * CC + kb + k] = f2bf(tile[k][n]);
        }
        return;
    }
    const float* W = (z == 0) ? W0 : (z == 1) ? W1 : (z == 2) ? W2 : W3;
    u16* Wt = (z == 0) ? T0 : (z == 1) ? T1 : (z == 2) ? T2 : T3;
    int nb = blockIdx.x * 64, kb = blockIdx.y * 64;
    for (int i = tid; i < 4096; i += 256) {
        int r = i >> 6, c = i & 63;
        tile[r][c] = W[(size_t)(kb + r) * CC + nb + c];
    }
    __syncthreads();
    for (int i = tid; i < 4096; i += 256) {
        int r = i >> 6, c = i & 63;
        Wt[(size_t)(nb + r) * CC + kb + c] = f2bf(tile[c][r]);
    }
}

// ---------------- K1 as MFMA GEMM, K-split x8 ----------------
// grid (128, 8) x 128 threads (2 waves); block owns 16 rows x 96 cols, K=256.
__global__ __launch_bounds__(128) void k_lgemm(const float* __restrict__ x,
                                               const float* __restrict__ shift,
                                               const float* __restrict__ maa_x,
                                               const u16* __restrict__ w1t,
                                               float* __restrict__ hp) {
    __shared__ u16 As[16 * 64];
    __shared__ u16 Bs[96 * 64];
    int tid = threadIdx.x, lane = tid & 63, wave = tid >> 6;
    int brow = blockIdx.x * 16;
    int kbeg = blockIdx.y * 256;

    int ar = tid >> 3, ag = tid & 7;
    int grow = brow + ar;
    int t = grow & (TT - 1), b = grow >> 10;
    const float* xr = x + (size_t)grow * CC;
    const float* xp = (t == 0) ? (shift + (size_t)b * CC) : (xr - CC);
    u16* adst = As + ar * 64 + ((ag ^ (ar & 7)) * 8);

    v4f acc[3];
    #pragma unroll
    for (int ni = 0; ni < 3; ++ni)
        #pragma unroll
        for (int e = 0; e < 4; ++e) acc[ni][e] = 0.f;

    for (int k0 = kbeg; k0 < kbeg + 256; k0 += 64) {
        __syncthreads();
        #pragma unroll
        for (int u = 0; u < 6; ++u) {
            int r = (wave * 6 + u) * 8 + (lane >> 3);
            int sc = ((lane & 7) ^ (r & 7)) * 8;
            gld16(w1t + (size_t)r * CC + k0 + sc, Bs + (wave * 6 + u) * 512);
        }
        {
            int kb_ = k0 + ag * 8;
            fx4 x0 = *reinterpret_cast<const fx4*>(xr + kb_);
            fx4 x1 = *reinterpret_cast<const fx4*>(xr + kb_ + 4);
            fx4 p0 = *reinterpret_cast<const fx4*>(xp + kb_);
            fx4 p1 = *reinterpret_cast<const fx4*>(xp + kb_ + 4);
            fx4 m0 = *reinterpret_cast<const fx4*>(maa_x + kb_);
            fx4 m1 = *reinterpret_cast<const fx4*>(maa_x + kb_ + 4);
            fx4 r0 = x0 + (p0 - x0) * m0;
            fx4 r1 = x1 + (p1 - x1) * m1;
            u16x8 a8;
            #pragma unroll
            for (int e = 0; e < 4; ++e) { a8[e] = f2bf(r0[e]); a8[e + 4] = f2bf(r1[e]); }
            *reinterpret_cast<u16x8*>(adst) = a8;
        }
        __syncthreads();

        #pragma unroll
        for (int ks = 0; ks < 2; ++ks) {
            int kg = ks * 4 + (lane >> 4);
            int rlA = lane & 15;
            v8s af = *reinterpret_cast<const v8s*>(As + rlA * 64 + ((kg ^ (rlA & 7)) * 8));
            #pragma unroll
            for (int ni = 0; ni < 3; ++ni) {
                int rlB = wave * 48 + ni * 16 + (lane & 15);
                v8s bf = *reinterpret_cast<const v8s*>(Bs + rlB * 64 + ((kg ^ (rlB & 7)) * 8));
                acc[ni] = __builtin_amdgcn_mfma_f32_16x16x32_bf16(af, bf, acc[ni], 0, 0, 0);
            }
        }
    }

    float* hpk = hp + (size_t)blockIdx.y * BT * 96;
    #pragma unroll
    for (int ni = 0; ni < 3; ++ni) {
        int col = wave * 48 + ni * 16 + (lane & 15);
        #pragma unroll
        for (int j = 0; j < 4; ++j) {
            int row = brow + (lane >> 4) * 4 + j;
            hpk[(size_t)row * 96 + col] = acc[ni][j];
        }
    }
}

// ---------------- reduce 8 partials + tanh ----------------
__global__ __launch_bounds__(256) void k_lred(const float* __restrict__ hp,
                                              float* __restrict__ h) {
    int i = (blockIdx.x * 256 + threadIdx.x) * 4;
    const size_t S = (size_t)BT * 96;
    fx4 s = *reinterpret_cast<const fx4*>(hp + i);
    #pragma unroll
    for (int p = 1; p < 8; ++p)
        s += *reinterpret_cast<const fx4*>(hp + (size_t)p * S + i);
    fx4 o;
    #pragma unroll
    for (int e = 0; e < 4; ++e) o[e] = tanhf(s[e]);
    *reinterpret_cast<fx4*>(h + i) = o;
}

// ---------------- K2: tiled mix ----------------
__global__ __launch_bounds__(256) void k_mix2(const float* __restrict__ x,
                                              const float* __restrict__ shift,
                                              const float* __restrict__ h_in,
                                              const float* __restrict__ w2,
                                              const float* __restrict__ maa_r,
                                              const float* __restrict__ maa_k,
                                              const float* __restrict__ maa_v,
                                              u16* __restrict__ oq,
                                              u16* __restrict__ ok,
                                              u16* __restrict__ ov) {
    __shared__ float w2s[96][64];
    __shared__ float hs[64][100];
    int tid = threadIdx.x;
    int c0 = blockIdx.x * 64, r0 = blockIdx.y * 64;
    for (int i = tid; i < 96 * 64; i += 256) {
        int r = i >> 6, c = i & 63;
        w2s[r][c] = w2[(size_t)r * CC + c0 + c];
    }
    for (int i = tid; i < 64 * 96; i += 256) {
        int r = i / 96, jj = i - r * 96;
        hs[r][jj] = h_in[(size_t)(r0 + r) * 96 + jj];
    }
    __syncthreads();

    int cq = tid & 15, rg = tid >> 4;
    int c = c0 + cq * 4;
    fx4 acc[4][3];
    #pragma unroll
    for (int r = 0; r < 4; ++r)
        #pragma unroll
        for (int l = 0; l < 3; ++l)
            #pragma unroll
            for (int e = 0; e < 4; ++e) acc[r][l][e] = 0.f;

    #pragma unroll 2
    for (int i4 = 0; i4 < 8; ++i4) {
        fx4 hv[4][3];
        #pragma unroll
        for (int r = 0; r < 4; ++r) {
            int row = rg * 4 + r;
            hv[r][0] = *reinterpret_cast<const fx4*>(&hs[row][i4 * 4]);
            hv[r][1] = *reinterpret_cast<const fx4*>(&hs[row][32 + i4 * 4]);
            hv[r][2] = *reinterpret_cast<const fx4*>(&hs[row][64 + i4 * 4]);
        }
        #pragma unroll
        for (int e = 0; e < 4; ++e) {
            int i = i4 * 4 + e;
            fx4 w0 = *reinterpret_cast<const fx4*>(&w2s[i][cq * 4]);
            fx4 w1v = *reinterpret_cast<const fx4*>(&w2s[32 + i][cq * 4]);
            fx4 w2v = *reinterpret_cast<const fx4*>(&w2s[64 + i][cq * 4]);
            #pragma unroll
            for (int r = 0; r < 4; ++r) {
                acc[r][0] += hv[r][0][e] * w0;
                acc[r][1] += hv[r][1][e] * w1v;
                acc[r][2] += hv[r][2][e] * w2v;
            }
        }
    }

    fx4 m_r = *reinterpret_cast<const fx4*>(maa_r + c);
    fx4 m_k = *reinterpret_cast<const fx4*>(maa_k + c);
    fx4 m_v = *reinterpret_cast<const fx4*>(maa_v + c);
    #pragma unroll
    for (int r = 0; r < 4; ++r) {
        int grow = r0 + rg * 4 + r;
        int t = grow & (TT - 1), b = grow >> 10;
        const float* xr = x + (size_t)grow * CC;
        const float* xp = (t == 0) ? (shift + (size_t)b * CC) : (xr - CC);
        fx4 xv = *reinterpret_cast<const fx4*>(xr + c);
        fx4 pv = *reinterpret_cast<const fx4*>(xp + c);
        fx4 dx = pv - xv;
        fx4 rq = xv + dx * (m_r + acc[r][0]);
        fx4 rk = xv + dx * (m_k + acc[r][1]);
        fx4 rv = xv + dx * (m_v + acc[r][2]);
        u16x4 pq, pk, pvv;
        #pragma unroll
        for (int e = 0; e < 4; ++e) { pq[e] = f2bf(rq[e]); pk[e] = f2bf(rk[e]); pvv[e] = f2bf(rv[e]); }
        size_t o = (size_t)grow * CC + c;
        *reinterpret_cast<u16x4*>(oq + o) = pq;
        *reinterpret_cast<u16x4*>(ok + o) = pk;
        *reinterpret_cast<u16x4*>(ov + o) = pvv;
    }
}

// ---------------- MFMA bf16 GEMM body (global_load_lds staging) ----------------
template <typename CT>
__device__ __forceinline__ void gemm_body(const u16* __restrict__ A,
                                          const u16* __restrict__ Bt,
                                          CT* __restrict__ C,
                                          int bm, int bn) {
    constexpr int Kd = 2048, Nd = 2048;
    __shared__ u16 As[128 * 64];
    __shared__ u16 Bs[128 * 64];
    int tid = threadIdx.x;
    int lane = tid & 63, wave = tid >> 6;
    int wr = wave >> 1, wc = wave & 1;

    int srow[4], scol[4];
    #pragma unroll
    for (int q = 0; q < 4; ++q) {
        int e = q * 2048 + wave * 512 + lane * 8;
        int row = e >> 6;
        srow[q] = row;
        scol[q] = ((lane & 7) ^ (row & 7)) * 8;
    }

    v4f acc[4][4];
    #pragma unroll
    for (int i = 0; i < 4; ++i)
        #pragma unroll
        for (int j = 0; j < 4; ++j)
            #pragma unroll
            for (int e = 0; e < 4; ++e) acc[i][j][e] = 0.f;

    for (int k0 = 0; k0 < Kd; k0 += 64) {
        __syncthreads();
        #pragma unroll
        for (int q = 0; q < 4; ++q)
            gld16(A + (size_t)(bm + srow[q]) * Kd + k0 + scol[q], As + q * 2048 + wave * 512);
        #pragma unroll
        for (int q = 0; q < 4; ++q)
            gld16(Bt + (size_t)(bn + srow[q]) * Kd + k0 + scol[q], Bs + q * 2048 + wave * 512);
        __syncthreads();
        #pragma unroll
        for (int ks = 0; ks < 2; ++ks) {
            int kg = ks * 4 + (lane >> 4);
            v8s af[4], bf[4];
            #pragma unroll
            for (int mi = 0; mi < 4; ++mi) {
                int rl = wr * 64 + mi * 16 + (lane & 15);
                af[mi] = *reinterpret_cast<const v8s*>(As + rl * 64 + ((kg ^ (rl & 7)) * 8));
            }
            #pragma unroll
            for (int ni = 0; ni < 4; ++ni) {
                int rl = wc * 64 + ni * 16 + (lane & 15);
                bf[ni] = *reinterpret_cast<const v8s*>(Bs + rl * 64 + ((kg ^ (rl & 7)) * 8));
            }
            #pragma unroll
            for (int mi = 0; mi < 4; ++mi)
                #pragma unroll
                for (int ni = 0; ni < 4; ++ni)
                    acc[mi][ni] = __builtin_amdgcn_mfma_f32_16x16x32_bf16(af[mi], bf[ni], acc[mi][ni], 0, 0, 0);
        }
    }

    int cr = (lane >> 4) * 4;
    int ccol = lane & 15;
    #pragma unroll
    for (int mi = 0; mi < 4; ++mi)
        #pragma unroll
        for (int ni = 0; ni < 4; ++ni) {
            CT* cp = C + (size_t)(bm + wr * 64 + mi * 16 + cr) * Nd + bn + wc * 64 + ni * 16 + ccol;
            #pragma unroll
            for (int j = 0; j < 4; ++j) cstore(cp + (size_t)j * Nd, acc[mi][ni][j]);
        }
}

__global__ __launch_bounds__(256) void k_gemm_qkv(const u16* A0, const u16* A1, const u16* A2,
                                                  const u16* B0, const u16* B1, const u16* B2,
                                                  u16* C0, u16* C1, u16* C2) {
    int z = blockIdx.y;
    const u16* A = (z == 0) ? A0 : (z == 1) ? A1 : A2;
    const u16* B = (z == 0) ? B0 : (z == 1) ? B1 : B2;
    u16* C = (z == 0) ? C0 : (z == 1) ? C1 : C2;
    int bx, by;
    xcd_map(blockIdx.x, bx, by);
    gemm_body<u16>(A, B, C, by * 128, bx * 128);
}

__global__ __launch_bounds__(256) void k_gemm1(const u16* __restrict__ A,
                                               const u16* __restrict__ Bt,
                                               float* __restrict__ C) {
    int bx, by;
    xcd_map(blockIdx.x, bx, by);
    gemm_body<float>(A, Bt, C, by * 128, bx * 128);
}

// ---------------- LayerNorm (bf16 in, bf16 out) ----------------
__global__ __launch_bounds__(256) void k_ln_bb(u16* __restrict__ y, const u16* __restrict__ xin,
                                               const float* __restrict__ g, const float* __restrict__ bb) {
    int row = blockIdx.x;
    const u16* xr = xin + (size_t)row * CC;
    int tid = threadIdx.x;
    u16x8 v8 = *reinterpret_cast<const u16x8*>(xr + tid * 8);
    float xv[8];
    float s = 0.f, ss = 0.f;
    #pragma unroll
    for (int e = 0; e < 8; ++e) { xv[e] = bf2f(v8[e]); s += xv[e]; ss += xv[e] * xv[e]; }
    #pragma unroll
    for (int o = 32; o > 0; o >>= 1) { s += __shfl_xor(s, o); ss += __shfl_xor(ss, o); }
    __shared__ float red[8];
    int wid = tid >> 6;
    if ((tid & 63) == 0) { red[wid] = s; red[wid + 4] = ss; }
    __syncthreads();
    s  = red[0] + red[1] + red[2] + red[3];
    ss = red[4] + red[5] + red[6] + red[7];
    float mu  = s * (1.0f / CC);
    float var = ss * (1.0f / CC) - mu * mu;
    float rsg = rsqrtf(var + 1e-5f);
    fx4 g0 = *reinterpret_cast<const fx4*>(g + tid * 8);
    fx4 g1 = *reinterpret_cast<const fx4*>(g + tid * 8 + 4);
    fx4 b0 = *reinterpret_cast<const fx4*>(bb + tid * 8);
    fx4 b1 = *reinterpret_cast<const fx4*>(bb + tid * 8 + 4);
    u16x8 o8;
    #pragma unroll
    for (int e = 0; e < 4; ++e) o8[e]     = f2bf((xv[e] - mu) * rsg * g0[e] + b0[e]);
    #pragma unroll
    for (int e = 0; e < 4; ++e) o8[e + 4] = f2bf((xv[e + 4] - mu) * rsg * g1[e] + b1[e]);
    *reinterpret_cast<u16x8*>(y + (size_t)row * CC + tid * 8) = o8;
}

// ---------------- fused LN(q)+LN(k)+LN(v)+RoPE(q,k), bf16->bf16 (q pre-scaled 1/8) ----------------
__global__ __launch_bounds__(256) void k_lnrope3(const u16* __restrict__ qin,
                                                 const u16* __restrict__ kin,
                                                 const u16* __restrict__ vin,
                                                 u16* __restrict__ qo, u16* __restrict__ ko,
                                                 u16* __restrict__ vo,
                                                 const float* __restrict__ g_r, const float* __restrict__ b_r,
                                                 const float* __restrict__ g_k, const float* __restrict__ b_k,
                                                 const float* __restrict__ g_v, const float* __restrict__ b_v,
                                                 const float* __restrict__ cosb, const float* __restrict__ sinb) {
    int row = blockIdx.x;
    int t = row & (TT - 1);
    int tid = threadIdx.x;
    const u16* qr_ = qin + (size_t)row * CC;
    const u16* kr_ = kin + (size_t)row * CC;
    const u16* vr_ = vin + (size_t)row * CC;
    float sq = 0.f, ssq = 0.f, sk = 0.f, ssk = 0.f, sv = 0.f, ssv = 0.f;
    float xv[8];
    {
        u16x8 qv = *reinterpret_cast<const u16x8*>(qr_ + tid * 8);
        u16x8 kv = *reinterpret_cast<const u16x8*>(kr_ + tid * 8);
        u16x8 vv = *reinterpret_cast<const u16x8*>(vr_ + tid * 8);
        #pragma unroll
        for (int e = 0; e < 8; ++e) {
            float qf = bf2f(qv[e]), kf = bf2f(kv[e]);
            xv[e] = bf2f(vv[e]);
            sq += qf; ssq += qf * qf;
            sk += kf; ssk += kf * kf;
            sv += xv[e]; ssv += xv[e] * xv[e];
        }
    }
    #pragma unroll
    for (int o_ = 32; o_ > 0; o_ >>= 1) {
        sq += __shfl_xor(sq, o_); ssq += __shfl_xor(ssq, o_);
        sk += __shfl_xor(sk, o_); ssk += __shfl_xor(ssk, o_);
        sv += __shfl_xor(sv, o_); ssv += __shfl_xor(ssv, o_);
    }
    __shared__ float red[24];
    int wid = tid >> 6;
    if ((tid & 63) == 0) {
        red[wid] = sq; red[wid + 4] = ssq;
        red[wid + 8] = sk; red[wid + 12] = ssk;
        red[wid + 16] = sv; red[wid + 20] = ssv;
    }
    __syncthreads();
    sq  = red[0] + red[1] + red[2] + red[3];
    ssq = red[4] + red[5] + red[6] + red[7];
    sk  = red[8] + red[9] + red[10] + red[11];
    ssk = red[12] + red[13] + red[14] + red[15];
    sv  = red[16] + red[17] + red[18] + red[19];
    ssv = red[20] + red[21] + red[22] + red[23];
    float muq = sq * (1.0f / CC), vq = ssq * (1.0f / CC) - muq * muq, rq = rsqrtf(vq + 1e-5f);
    float muk = sk * (1.0f / CC), vk = ssk * (1.0f / CC) - muk * muk, rk = rsqrtf(vk + 1e-5f);
    float muv = sv * (1.0f / CC), vv_ = ssv * (1.0f / CC) - muv * muv, rv = rsqrtf(vv_ + 1e-5f);

    // V: straight LN, vectorized
    {
        fx4 g0 = *reinterpret_cast<const fx4*>(g_v + tid * 8);
        fx4 g1 = *reinterpret_cast<const fx4*>(g_v + tid * 8 + 4);
        fx4 b0 = *reinterpret_cast<const fx4*>(b_v + tid * 8);
        fx4 b1 = *reinterpret_cast<const fx4*>(b_v + tid * 8 + 4);
        u16x8 o8;
        #pragma unroll
        for (int e = 0; e < 4; ++e) o8[e]     = f2bf((xv[e] - muv) * rv * g0[e] + b0[e]);
        #pragma unroll
        for (int e = 0; e < 4; ++e) o8[e + 4] = f2bf((xv[e + 4] - muv) * rv * g1[e] + b1[e]);
        *reinterpret_cast<u16x8*>(vo + (size_t)row * CC + tid * 8) = o8;
    }

    // Q,K: LN + RoPE
    #pragma unroll
    for (int i = 0; i < 4; ++i) {
        int p = tid + i * 256;
        int h = p >> 5, d = p & 31;
        int c1 = h * 64 + d, c2 = c1 + 32;
        float cv = cosb[t * 32 + d], sv2 = sinb[t * 32 + d];
        float q1 = (bf2f(qr_[c1]) - muq) * rq * g_r[c1] + b_r[c1];
        float q2 = (bf2f(qr_[c2]) - muq) * rq * g_r[c2] + b_r[c2];
        qo[(size_t)row * CC + c1] = f2bf((q1 * cv - q2 * sv2) * 0.125f);
        qo[(size_t)row * CC + c2] = f2bf((q1 * sv2 + q2 * cv) * 0.125f);
        float k1 = (bf2f(kr_[c1]) - muk) * rk * g_k[c1] + b_k[c1];
        float k2 = (bf2f(kr_[c2]) - muk) * rk * g_k[c2] + b_k[c2];
        ko[(size_t)row * CC + c1] = f2bf(k1 * cv - k2 * sv2);
        ko[(size_t)row * CC + c2] = f2bf(k1 * sv2 + k2 * cv);
    }
}

// ---------------- V transpose: [b*TT+t][CC] -> [(b*HH+h)*KD+d][TT] ----------------
__global__ __launch_bounds__(256) void k_vtr(const u16* __restrict__ vin,
                                             u16* __restrict__ vout) {
    int t0 = blockIdx.x * 64, h = blockIdx.y, b = blockIdx.z;
    __shared__ u16 tile[64][72];
    int tid = threadIdx.x;
    #pragma unroll
    for (int u = 0; u < 2; ++u) {
        int g = tid + u * 256;
        int r = g >> 3, gc = g & 7;
        u16x8 vv = *reinterpret_cast<const u16x8*>(vin + (size_t)(b * TT + t0 + r) * CC + h * 64 + gc * 8);
        *reinterpret_cast<u16x8*>(&tile[r][gc * 8]) = vv;
    }
    __syncthreads();
    #pragma unroll
    for (int u = 0; u < 2; ++u) {
        int g = tid + u * 256;
        int d = g >> 3, tc = g & 7;
        u16x8 ov;
        #pragma unroll
        for (int e = 0; e < 8; ++e) ov[e] = tile[tc * 8 + e][d];
        *reinterpret_cast<u16x8*>(vout + ((size_t)(b * HH + h) * KD + d) * TT + t0 + tc * 8) = ov;
    }
}

// ---------------- MFMA bf16 flash attention: TRIPLE-buffered K/V, ONE barrier/tile ----------------
// Invariant: at the barrier opening tile kt, every wave has finished computing tile kt-1,
// so slot (kt+2)%3 == (kt-1)%3 is free to restage immediately after that barrier.
// Per-wave vmcnt: steady-state outstanding = {kt, kt+1} (4 loads) -> vmcnt(2) drains kt.
__global__ __launch_bounds__(512) void k_mattn3(const u16* __restrict__ q,
                                                const u16* __restrict__ k,
                                                const u16* __restrict__ vt,
                                                u16* __restrict__ o) {
    int st = (int)gridDim.x - 1 - (int)blockIdx.x;
    int h = blockIdx.y, b = blockIdx.z;
    __shared__ u16 Ks[3][64 * 64];
    __shared__ u16 Vs[3][64 * 64];
    __shared__ u16 Ps[8][16 * 64];
    int tid = threadIdx.x, lane = tid & 63, wave = tid >> 6;
    size_t bh = (size_t)b * TT * CC + (size_t)h * KD;
    const u16* vth = vt + (size_t)(b * HH + h) * KD * TT;
    int qrow0 = st * 128 + wave * 16;

    v8s qf[2];
    {
        const u16* qp = q + bh + (size_t)(qrow0 + (lane & 15)) * CC + (lane >> 4) * 8;
        qf[0] = *reinterpret_cast<const v8s*>(qp);
        qf[1] = *reinterpret_cast<const v8s*>(qp + 32);
    }

    float mstat[4], lstat[4];
    v4f oacc[4];
    #pragma unroll
    for (int j = 0; j < 4; ++j) { mstat[j] = -1e30f; lstat[j] = 0.f; }
    #pragma unroll
    for (int nd = 0; nd < 4; ++nd)
        #pragma unroll
        for (int e = 0; e < 4; ++e) oacc[nd][e] = 0.f;

    int srow = (wave << 3) + (lane >> 3);
    int scol = ((lane & 7) ^ (srow & 7)) << 3;
    u16* pw = Ps[wave];
    int ktmax = 2 * st + 1;

    auto STAGE = [&](int slot, int kt) {
        gld16(k + bh + (size_t)(kt * 64 + srow) * CC + scol, &Ks[slot][wave * 512]);
        gld16(vth + (size_t)srow * TT + kt * 64 + scol, &Vs[slot][wave * 512]);
    };

    STAGE(0, 0);
    STAGE(1, 1);            // ktmax >= 1 always

    for (int kt = 0; kt <= ktmax; ++kt) {
        int cur = kt % 3;
        if (kt < ktmax) asm volatile("s_waitcnt vmcnt(2)" ::: "memory");
        else            asm volatile("s_waitcnt vmcnt(0)" ::: "memory");
        __builtin_amdgcn_s_barrier();       // single barrier: kt landed AND all done with kt-1
        __builtin_amdgcn_sched_barrier(0);
        if (kt + 2 <= ktmax) STAGE((kt + 2) % 3, kt + 2);   // into slot freed by kt-1

        if (kt * 64 <= qrow0 + 15) {
            const u16* KsC = Ks[cur];
            const u16* VsC = Vs[cur];

            v4f s[4];
            __builtin_amdgcn_s_setprio(1);
            #pragma unroll
            for (int ni = 0; ni < 4; ++ni) {
                #pragma unroll
                for (int e = 0; e < 4; ++e) s[ni][e] = 0.f;
                #pragma unroll
                for (int ks = 0; ks < 2; ++ks) {
                    int rl = ni * 16 + (lane & 15);
                    int kg = ks * 4 + (lane >> 4);
                    int swz = kg ^ (rl & 7);
                    v8s kf = *reinterpret_cast<const v8s*>(KsC + rl * 64 + swz * 8);
                    s[ni] = __builtin_amdgcn_mfma_f32_16x16x32_bf16(qf[ks], kf, s[ni], 0, 0, 0);
                }
            }
            __builtin_amdgcn_s_setprio(0);
            if (kt * 64 + 63 > qrow0) {
                int qr = qrow0 + (lane >> 4) * 4;
                int kc = kt * 64 + (lane & 15);
                #pragma unroll
                for (int ni = 0; ni < 4; ++ni)
                    #pragma unroll
                    for (int j = 0; j < 4; ++j)
                        if (kc + ni * 16 > qr + j) s[ni][j] = -1e30f;
            }

            float alpha[4];
            #pragma unroll
            for (int j = 0; j < 4; ++j) {
                float pm = fmaxf(fmaxf(s[0][j], s[1][j]), fmaxf(s[2][j], s[3][j]));
                pm = fmaxf(pm, __shfl_xor(pm, 1));
                pm = fmaxf(pm, __shfl_xor(pm, 2));
                pm = fmaxf(pm, __shfl_xor(pm, 4));
                pm = fmaxf(pm, __shfl_xor(pm, 8));
                float mn = fmaxf(mstat[j], pm);
                alpha[j] = __expf(mstat[j] - mn);
                float rs = 0.f;
                #pragma unroll
                for (int ni = 0; ni < 4; ++ni) {
                    float p = __expf(s[ni][j] - mn);
                    s[ni][j] = p;
                    rs += p;
                }
                rs += __shfl_xor(rs, 1);
                rs += __shfl_xor(rs, 2);
                rs += __shfl_xor(rs, 4);
                rs += __shfl_xor(rs, 8);
                lstat[j] = lstat[j] * alpha[j] + rs;
                mstat[j] = mn;
            }
            #pragma unroll
            for (int nd = 0; nd < 4; ++nd)
                #pragma unroll
                for (int j = 0; j < 4; ++j) oacc[nd][j] *= alpha[j];

            #pragma unroll
            for (int ni = 0; ni < 4; ++ni) {
                int kc = (lane & 15) + ni * 16;
                #pragma unroll
                for (int j = 0; j < 4; ++j) {
                    int qr = (lane >> 4) * 4 + j;
                    int swz = (kc >> 3) ^ (qr & 7) ^ (qr >> 3);
                    pw[qr * 64 + swz * 8 + (kc & 7)] = f2bf(s[ni][j]);
                }
            }

            v8s pf[2];
            #pragma unroll
            for (int ks = 0; ks < 2; ++ks) {
                int prow = lane & 15;
                int kg = ks * 4 + (lane >> 4);
                int swz = kg ^ (prow & 7) ^ (prow >> 3);
                pf[ks] = *reinterpret_cast<const v8s*>(pw + prow * 64 + swz * 8);
            }
            __builtin_amdgcn_s_setprio(1);
            #pragma unroll
            for (int nd = 0; nd < 4; ++nd) {
                #pragma unroll
                for (int ks = 0; ks < 2; ++ks) {
                    int vrow = nd * 16 + (lane & 15);
                    int vg = ks * 4 + (lane >> 4);
                    int vswz = vg ^ (vrow & 7);
                    v8s vf = *reinterpret_cast<const v8s*>(VsC + vrow * 64 + vswz * 8);
                    oacc[nd] = __builtin_amdgcn_mfma_f32_16x16x32_bf16(pf[ks], vf, oacc[nd], 0, 0, 0);
                }
            }
            __builtin_amdgcn_s_setprio(0);
        }
    }

    #pragma unroll
    for (int j = 0; j < 4; ++j) {
        int qrow = qrow0 + (lane >> 4) * 4 + j;
        float inv = 1.0f / lstat[j];
        #pragma unroll
        for (int nd = 0; nd < 4; ++nd)
            o[bh + (size_t)qrow * CC + (lane & 15) + nd * 16] = f2bf(oacc[nd][j] * inv);
    }
}

extern "C" void kernel_launch(void* const* d_in, const int* in_sizes, int n_in,
                              void* d_out, int out_size, void* d_ws, size_t ws_size,
                              hipStream_t stream) {
    const float* x     = (const float*)d_in[0];
    const float* shift = (const float*)d_in[1];
    const float* maa_x = (const float*)d_in[2];
    const float* maa_r = (const float*)d_in[3];
    const float* maa_k = (const float*)d_in[4];
    const float* maa_v = (const float*)d_in[5];
    const float* w1    = (const float*)d_in[6];
    const float* w2    = (const float*)d_in[7];
    const float* Wq    = (const float*)d_in[8];
    const float* Wk    = (const float*)d_in[9];
    const float* Wv    = (const float*)d_in[10];
    const float* Wo    = (const float*)d_in[11];
    const float* g_r   = (const float*)d_in[12];
    const float* b_r   = (const float*)d_in[13];
    const float* g_k   = (const float*)d_in[14];
    const float* b_k   = (const float*)d_in[15];
    const float* g_v   = (const float*)d_in[16];
    const float* b_v   = (const float*)d_in[17];
    const float* g_x   = (const float*)d_in[18];
    const float* b_x   = (const float*)d_in[19];
    const float* cosb  = (const float*)d_in[20];
    const float* sinb  = (const float*)d_in[21];

    char* w = (char*)d_ws;
    const size_t WB = (size_t)BT * CC * 2;     // 8 MiB bf16 plane
    u16*   wtq  = (u16*)(w + 0 * WB);
    u16*   wtk  = (u16*)(w + 1 * WB);
    u16*   wtv  = (u16*)(w + 2 * WB);
    u16*   xqb  = (u16*)(w + 3 * WB);
    u16*   xkb  = (u16*)(w + 4 * WB);
    u16*   xvb  = (u16*)(w + 5 * WB);
    u16*   qb16 = (u16*)(w + 6 * WB);
    u16*   kb16 = (u16*)(w + 7 * WB);
    u16*   vb16 = (u16*)(w + 8 * WB);
    u16*   vtb  = (u16*)(w + 9 * WB);
    float* hp   = (float*)(w + 10 * WB);                 // 6.29 MB (8 partial slices)
    float* hb   = (float*)(w + 10 * WB + 0x600000);      // 786 KB
    u16*   w1t  = (u16*)(w + 10 * WB + 0x700000);        // 384 KB
    u16*   wto  = (u16*)(w + 11 * WB);
    // aliases over consumed planes:
    u16*   qbb = (u16*)(w + 3 * WB);           // roped Q over xqb
    u16*   kbb = (u16*)(w + 4 * WB);           // roped K over xkb
    u16*   vbb = (u16*)(w + 5 * WB);           // LN'd V over xvb
    u16*   ob  = (u16*)(w + 6 * WB);           // attn out over qb16
    u16*   oln = (u16*)(w + 7 * WB);           // LN(attn) over kb16
    float* out = (float*)d_out;

    k_tconv5<<<dim3(32, 32, 5), 256, 0, stream>>>(Wq, Wk, Wv, Wo, w1,
                                                  wtq, wtk, wtv, wto, w1t);

    k_lgemm<<<dim3(BT / 16, 8), 128, 0, stream>>>(x, shift, maa_x, w1t, hp);
    k_lred<<<BT * 96 / 1024, 256, 0, stream>>>(hp, hb);
    k_mix2<<<dim3(32, 32), 256, 0, stream>>>(x, shift, hb, w2, maa_r, maa_k, maa_v,
                                             xqb, xkb, xvb);

    k_gemm_qkv<<<dim3(256, 3), 256, 0, stream>>>(xqb, xkb, xvb, wtq, wtk, wtv,
                                                 qb16, kb16, vb16);

    k_lnrope3<<<BT, 256, 0, stream>>>(qb16, kb16, vb16, qbb, kbb, vbb,
                                      g_r, b_r, g_k, b_k, g_v, b_v, cosb, sinb);
    k_vtr<<<dim3(TT / 64, HH, BB), 256, 0, stream>>>(vbb, vtb);

    k_mattn3<<<dim3(TT / 128, HH, BB), 512, 0, stream>>>(qbb, kbb, vtb, ob);

    k_ln_bb<<<BT, 256, 0, stream>>>(oln, ob, g_x, b_x);
    k_gemm1<<<256, 256, 0, stream>>>(oln, wto, out);
}

// Round 13
// 217.863 us; speedup vs baseline: 1.0489x; 1.0489x over previous
//
#include <hip/hip_runtime.h>
#include <math.h>

static constexpr int BB = 2;
static constexpr int TT = 1024;
static constexpr int CC = 2048;
static constexpr int HH = 32;
static constexpr int KD = 64;
static constexpr int BT = BB * TT;

typedef short   v8s  __attribute__((ext_vector_type(8)));
typedef float   v4f  __attribute__((ext_vector_type(4)));
typedef unsigned short u16;
typedef u16     u16x8 __attribute__((ext_vector_type(8)));
typedef u16     u16x4 __attribute__((ext_vector_type(4)));
typedef float   fx4  __attribute__((ext_vector_type(4)));

__device__ __forceinline__ u16 f2bf(float f) {
    unsigned u = __builtin_bit_cast(unsigned, f);
    u = u + 0x7FFFu + ((u >> 16) & 1u);   // RNE
    return (u16)(u >> 16);
}
__device__ __forceinline__ float bf2f(u16 v) {
    return __builtin_bit_cast(float, ((unsigned)v) << 16);
}

// async global->LDS, 16B per lane; dest is wave-uniform base + lane*16
__device__ __forceinline__ void gld16(const u16* g, u16* l) {
    __builtin_amdgcn_global_load_lds(
        (const __attribute__((address_space(1))) void*)g,
        (__attribute__((address_space(3))) void*)l, 16, 0, 0);
}

__device__ __forceinline__ void cstore(float* p, float v) { *p = v; }
__device__ __forceinline__ void cstore(u16* p, float v)   { *p = f2bf(v); }

// XCD chunk swizzle: 256 blocks -> 16x16 tile grid, each XCD a 4x8 chunk
__device__ __forceinline__ void xcd_map(int bid, int& bx, int& by) {
    int i = bid & 7;
    int j = bid >> 3;
    bx = (i & 3) * 4 + (j & 3);
    by = (i >> 2) * 8 + (j >> 2);
}

// ---------------- transpose-convert weights (z<4) + w1 (z==4) ----------------
__global__ __launch_bounds__(256) void k_tconv5(const float* __restrict__ W0,
                                                const float* __restrict__ W1,
                                                const float* __restrict__ W2,
                                                const float* __restrict__ W3,
                                                const float* __restrict__ w1,
                                                u16* __restrict__ T0, u16* __restrict__ T1,
                                                u16* __restrict__ T2, u16* __restrict__ T3,
                                                u16* __restrict__ w1t) {
    __shared__ float tile[64][97];
    int tid = threadIdx.x;
    int z = blockIdx.z;
    if (z == 4) {                              // w1 f32 [2048][96] -> bf16 [96][2048]
        if (blockIdx.y != 0) return;
        int kb = blockIdx.x * 64;
        for (int i = tid; i < 64 * 96; i += 256) {
            int r = i / 96, c = i - r * 96;
            tile[r][c] = w1[(size_t)(kb + r) * 96 + c];
        }
        __syncthreads();
        for (int i = tid; i < 96 * 64; i += 256) {
            int n = i >> 6, k = i & 63;
            w1t[(size_t)n * CC + kb + k] = f2bf(tile[k][n]);
        }
        return;
    }
    const float* W = (z == 0) ? W0 : (z == 1) ? W1 : (z == 2) ? W2 : W3;
    u16* Wt = (z == 0) ? T0 : (z == 1) ? T1 : (z == 2) ? T2 : T3;
    int nb = blockIdx.x * 64, kb = blockIdx.y * 64;
    for (int i = tid; i < 4096; i += 256) {
        int r = i >> 6, c = i & 63;
        tile[r][c] = W[(size_t)(kb + r) * CC + nb + c];
    }
    __syncthreads();
    for (int i = tid; i < 4096; i += 256) {
        int r = i >> 6, c = i & 63;
        Wt[(size_t)(nb + r) * CC + kb + c] = f2bf(tile[c][r]);
    }
}

// ---------------- K1 as MFMA GEMM, K-split x8 ----------------
__global__ __launch_bounds__(128) void k_lgemm(const float* __restrict__ x,
                                               const float* __restrict__ shift,
                                               const float* __restrict__ maa_x,
                                               const u16* __restrict__ w1t,
                                               float* __restrict__ hp) {
    __shared__ u16 As[16 * 64];
    __shared__ u16 Bs[96 * 64];
    int tid = threadIdx.x, lane = tid & 63, wave = tid >> 6;
    int brow = blockIdx.x * 16;
    int kbeg = blockIdx.y * 256;

    int ar = tid >> 3, ag = tid & 7;
    int grow = brow + ar;
    int t = grow & (TT - 1), b = grow >> 10;
    const float* xr = x + (size_t)grow * CC;
    const float* xp = (t == 0) ? (shift + (size_t)b * CC) : (xr - CC);
    u16* adst = As + ar * 64 + ((ag ^ (ar & 7)) * 8);

    v4f acc[3];
    #pragma unroll
    for (int ni = 0; ni < 3; ++ni)
        #pragma unroll
        for (int e = 0; e < 4; ++e) acc[ni][e] = 0.f;

    for (int k0 = kbeg; k0 < kbeg + 256; k0 += 64) {
        __syncthreads();
        #pragma unroll
        for (int u = 0; u < 6; ++u) {
            int r = (wave * 6 + u) * 8 + (lane >> 3);
            int sc = ((lane & 7) ^ (r & 7)) * 8;
            gld16(w1t + (size_t)r * CC + k0 + sc, Bs + (wave * 6 + u) * 512);
        }
        {
            int kb_ = k0 + ag * 8;
            fx4 x0 = *reinterpret_cast<const fx4*>(xr + kb_);
            fx4 x1 = *reinterpret_cast<const fx4*>(xr + kb_ + 4);
            fx4 p0 = *reinterpret_cast<const fx4*>(xp + kb_);
            fx4 p1 = *reinterpret_cast<const fx4*>(xp + kb_ + 4);
            fx4 m0 = *reinterpret_cast<const fx4*>(maa_x + kb_);
            fx4 m1 = *reinterpret_cast<const fx4*>(maa_x + kb_ + 4);
            fx4 r0 = x0 + (p0 - x0) * m0;
            fx4 r1 = x1 + (p1 - x1) * m1;
            u16x8 a8;
            #pragma unroll
            for (int e = 0; e < 4; ++e) { a8[e] = f2bf(r0[e]); a8[e + 4] = f2bf(r1[e]); }
            *reinterpret_cast<u16x8*>(adst) = a8;
        }
        __syncthreads();

        #pragma unroll
        for (int ks = 0; ks < 2; ++ks) {
            int kg = ks * 4 + (lane >> 4);
            int rlA = lane & 15;
            v8s af = *reinterpret_cast<const v8s*>(As + rlA * 64 + ((kg ^ (rlA & 7)) * 8));
            #pragma unroll
            for (int ni = 0; ni < 3; ++ni) {
                int rlB = wave * 48 + ni * 16 + (lane & 15);
                v8s bf = *reinterpret_cast<const v8s*>(Bs + rlB * 64 + ((kg ^ (rlB & 7)) * 8));
                acc[ni] = __builtin_amdgcn_mfma_f32_16x16x32_bf16(af, bf, acc[ni], 0, 0, 0);
            }
        }
    }

    float* hpk = hp + (size_t)blockIdx.y * BT * 96;
    #pragma unroll
    for (int ni = 0; ni < 3; ++ni) {
        int col = wave * 48 + ni * 16 + (lane & 15);
        #pragma unroll
        for (int j = 0; j < 4; ++j) {
            int row = brow + (lane >> 4) * 4 + j;
            hpk[(size_t)row * 96 + col] = acc[ni][j];
        }
    }
}

// ---------------- reduce 8 partials + tanh ----------------
__global__ __launch_bounds__(256) void k_lred(const float* __restrict__ hp,
                                              float* __restrict__ h) {
    int i = (blockIdx.x * 256 + threadIdx.x) * 4;
    const size_t S = (size_t)BT * 96;
    fx4 s = *reinterpret_cast<const fx4*>(hp + i);
    #pragma unroll
    for (int p = 1; p < 8; ++p)
        s += *reinterpret_cast<const fx4*>(hp + (size_t)p * S + i);
    fx4 o;
    #pragma unroll
    for (int e = 0; e < 4; ++e) o[e] = tanhf(s[e]);
    *reinterpret_cast<fx4*>(h + i) = o;
}

// ---------------- K2: tiled mix ----------------
__global__ __launch_bounds__(256) void k_mix2(const float* __restrict__ x,
                                              const float* __restrict__ shift,
                                              const float* __restrict__ h_in,
                                              const float* __restrict__ w2,
                                              const float* __restrict__ maa_r,
                                              const float* __restrict__ maa_k,
                                              const float* __restrict__ maa_v,
                                              u16* __restrict__ oq,
                                              u16* __restrict__ ok,
                                              u16* __restrict__ ov) {
    __shared__ float w2s[96][64];
    __shared__ float hs[64][100];
    int tid = threadIdx.x;
    int c0 = blockIdx.x * 64, r0 = blockIdx.y * 64;
    for (int i = tid; i < 96 * 64; i += 256) {
        int r = i >> 6, c = i & 63;
        w2s[r][c] = w2[(size_t)r * CC + c0 + c];
    }
    for (int i = tid; i < 64 * 96; i += 256) {
        int r = i / 96, jj = i - r * 96;
        hs[r][jj] = h_in[(size_t)(r0 + r) * 96 + jj];
    }
    __syncthreads();

    int cq = tid & 15, rg = tid >> 4;
    int c = c0 + cq * 4;
    fx4 acc[4][3];
    #pragma unroll
    for (int r = 0; r < 4; ++r)
        #pragma unroll
        for (int l = 0; l < 3; ++l)
            #pragma unroll
            for (int e = 0; e < 4; ++e) acc[r][l][e] = 0.f;

    #pragma unroll 2
    for (int i4 = 0; i4 < 8; ++i4) {
        fx4 hv[4][3];
        #pragma unroll
        for (int r = 0; r < 4; ++r) {
            int row = rg * 4 + r;
            hv[r][0] = *reinterpret_cast<const fx4*>(&hs[row][i4 * 4]);
            hv[r][1] = *reinterpret_cast<const fx4*>(&hs[row][32 + i4 * 4]);
            hv[r][2] = *reinterpret_cast<const fx4*>(&hs[row][64 + i4 * 4]);
        }
        #pragma unroll
        for (int e = 0; e < 4; ++e) {
            int i = i4 * 4 + e;
            fx4 w0 = *reinterpret_cast<const fx4*>(&w2s[i][cq * 4]);
            fx4 w1v = *reinterpret_cast<const fx4*>(&w2s[32 + i][cq * 4]);
            fx4 w2v = *reinterpret_cast<const fx4*>(&w2s[64 + i][cq * 4]);
            #pragma unroll
            for (int r = 0; r < 4; ++r) {
                acc[r][0] += hv[r][0][e] * w0;
                acc[r][1] += hv[r][1][e] * w1v;
                acc[r][2] += hv[r][2][e] * w2v;
            }
        }
    }

    fx4 m_r = *reinterpret_cast<const fx4*>(maa_r + c);
    fx4 m_k = *reinterpret_cast<const fx4*>(maa_k + c);
    fx4 m_v = *reinterpret_cast<const fx4*>(maa_v + c);
    #pragma unroll
    for (int r = 0; r < 4; ++r) {
        int grow = r0 + rg * 4 + r;
        int t = grow & (TT - 1), b = grow >> 10;
        const float* xr = x + (size_t)grow * CC;
        const float* xp = (t == 0) ? (shift + (size_t)b * CC) : (xr - CC);
        fx4 xv = *reinterpret_cast<const fx4*>(xr + c);
        fx4 pv = *reinterpret_cast<const fx4*>(xp + c);
        fx4 dx = pv - xv;
        fx4 rq = xv + dx * (m_r + acc[r][0]);
        fx4 rk = xv + dx * (m_k + acc[r][1]);
        fx4 rv = xv + dx * (m_v + acc[r][2]);
        u16x4 pq, pk, pvv;
        #pragma unroll
        for (int e = 0; e < 4; ++e) { pq[e] = f2bf(rq[e]); pk[e] = f2bf(rk[e]); pvv[e] = f2bf(rv[e]); }
        size_t o = (size_t)grow * CC + c;
        *reinterpret_cast<u16x4*>(oq + o) = pq;
        *reinterpret_cast<u16x4*>(ok + o) = pk;
        *reinterpret_cast<u16x4*>(ov + o) = pvv;
    }
}

// ---------------- MFMA bf16 GEMM body (global_load_lds staging) ----------------
template <typename CT>
__device__ __forceinline__ void gemm_body(const u16* __restrict__ A,
                                          const u16* __restrict__ Bt,
                                          CT* __restrict__ C,
                                          int bm, int bn) {
    constexpr int Kd = 2048, Nd = 2048;
    __shared__ u16 As[128 * 64];
    __shared__ u16 Bs[128 * 64];
    int tid = threadIdx.x;
    int lane = tid & 63, wave = tid >> 6;
    int wr = wave >> 1, wc = wave & 1;

    int srow[4], scol[4];
    #pragma unroll
    for (int q = 0; q < 4; ++q) {
        int e = q * 2048 + wave * 512 + lane * 8;
        int row = e >> 6;
        srow[q] = row;
        scol[q] = ((lane & 7) ^ (row & 7)) * 8;
    }

    v4f acc[4][4];
    #pragma unroll
    for (int i = 0; i < 4; ++i)
        #pragma unroll
        for (int j = 0; j < 4; ++j)
            #pragma unroll
            for (int e = 0; e < 4; ++e) acc[i][j][e] = 0.f;

    for (int k0 = 0; k0 < Kd; k0 += 64) {
        __syncthreads();
        #pragma unroll
        for (int q = 0; q < 4; ++q)
            gld16(A + (size_t)(bm + srow[q]) * Kd + k0 + scol[q], As + q * 2048 + wave * 512);
        #pragma unroll
        for (int q = 0; q < 4; ++q)
            gld16(Bt + (size_t)(bn + srow[q]) * Kd + k0 + scol[q], Bs + q * 2048 + wave * 512);
        __syncthreads();
        #pragma unroll
        for (int ks = 0; ks < 2; ++ks) {
            int kg = ks * 4 + (lane >> 4);
            v8s af[4], bf[4];
            #pragma unroll
            for (int mi = 0; mi < 4; ++mi) {
                int rl = wr * 64 + mi * 16 + (lane & 15);
                af[mi] = *reinterpret_cast<const v8s*>(As + rl * 64 + ((kg ^ (rl & 7)) * 8));
            }
            #pragma unroll
            for (int ni = 0; ni < 4; ++ni) {
                int rl = wc * 64 + ni * 16 + (lane & 15);
                bf[ni] = *reinterpret_cast<const v8s*>(Bs + rl * 64 + ((kg ^ (rl & 7)) * 8));
            }
            #pragma unroll
            for (int mi = 0; mi < 4; ++mi)
                #pragma unroll
                for (int ni = 0; ni < 4; ++ni)
                    acc[mi][ni] = __builtin_amdgcn_mfma_f32_16x16x32_bf16(af[mi], bf[ni], acc[mi][ni], 0, 0, 0);
        }
    }

    int cr = (lane >> 4) * 4;
    int ccol = lane & 15;
    #pragma unroll
    for (int mi = 0; mi < 4; ++mi)
        #pragma unroll
        for (int ni = 0; ni < 4; ++ni) {
            CT* cp = C + (size_t)(bm + wr * 64 + mi * 16 + cr) * Nd + bn + wc * 64 + ni * 16 + ccol;
            #pragma unroll
            for (int j = 0; j < 4; ++j) cstore(cp + (size_t)j * Nd, acc[mi][ni][j]);
        }
}

__global__ __launch_bounds__(256) void k_gemm_qkv(const u16* A0, const u16* A1, const u16* A2,
                                                  const u16* B0, const u16* B1, const u16* B2,
                                                  u16* C0, u16* C1, u16* C2) {
    int z = blockIdx.y;
    const u16* A = (z == 0) ? A0 : (z == 1) ? A1 : A2;
    const u16* B = (z == 0) ? B0 : (z == 1) ? B1 : B2;
    u16* C = (z == 0) ? C0 : (z == 1) ? C1 : C2;
    int bx, by;
    xcd_map(blockIdx.x, bx, by);
    gemm_body<u16>(A, B, C, by * 128, bx * 128);
}

__global__ __launch_bounds__(256) void k_gemm1(const u16* __restrict__ A,
                                               const u16* __restrict__ Bt,
                                               float* __restrict__ C) {
    int bx, by;
    xcd_map(blockIdx.x, bx, by);
    gemm_body<float>(A, Bt, C, by * 128, bx * 128);
}

// ---------------- LayerNorm (bf16 in, bf16 out) ----------------
__global__ __launch_bounds__(256) void k_ln_bb(u16* __restrict__ y, const u16* __restrict__ xin,
                                               const float* __restrict__ g, const float* __restrict__ bb) {
    int row = blockIdx.x;
    const u16* xr = xin + (size_t)row * CC;
    int tid = threadIdx.x;
    u16x8 v8 = *reinterpret_cast<const u16x8*>(xr + tid * 8);
    float xv[8];
    float s = 0.f, ss = 0.f;
    #pragma unroll
    for (int e = 0; e < 8; ++e) { xv[e] = bf2f(v8[e]); s += xv[e]; ss += xv[e] * xv[e]; }
    #pragma unroll
    for (int o = 32; o > 0; o >>= 1) { s += __shfl_xor(s, o); ss += __shfl_xor(ss, o); }
    __shared__ float red[8];
    int wid = tid >> 6;
    if ((tid & 63) == 0) { red[wid] = s; red[wid + 4] = ss; }
    __syncthreads();
    s  = red[0] + red[1] + red[2] + red[3];
    ss = red[4] + red[5] + red[6] + red[7];
    float mu  = s * (1.0f / CC);
    float var = ss * (1.0f / CC) - mu * mu;
    float rsg = rsqrtf(var + 1e-5f);
    fx4 g0 = *reinterpret_cast<const fx4*>(g + tid * 8);
    fx4 g1 = *reinterpret_cast<const fx4*>(g + tid * 8 + 4);
    fx4 b0 = *reinterpret_cast<const fx4*>(bb + tid * 8);
    fx4 b1 = *reinterpret_cast<const fx4*>(bb + tid * 8 + 4);
    u16x8 o8;
    #pragma unroll
    for (int e = 0; e < 4; ++e) o8[e]     = f2bf((xv[e] - mu) * rsg * g0[e] + b0[e]);
    #pragma unroll
    for (int e = 0; e < 4; ++e) o8[e + 4] = f2bf((xv[e + 4] - mu) * rsg * g1[e] + b1[e]);
    *reinterpret_cast<u16x8*>(y + (size_t)row * CC + tid * 8) = o8;
}

// ---------------- fused LN(q)+LN(k)+LN(v)+RoPE(q,k), bf16->bf16 (q pre-scaled 1/8) ----------------
__global__ __launch_bounds__(256) void k_lnrope3(const u16* __restrict__ qin,
                                                 const u16* __restrict__ kin,
                                                 const u16* __restrict__ vin,
                                                 u16* __restrict__ qo, u16* __restrict__ ko,
                                                 u16* __restrict__ vo,
                                                 const float* __restrict__ g_r, const float* __restrict__ b_r,
                                                 const float* __restrict__ g_k, const float* __restrict__ b_k,
                                                 const float* __restrict__ g_v, const float* __restrict__ b_v,
                                                 const float* __restrict__ cosb, const float* __restrict__ sinb) {
    int row = blockIdx.x;
    int t = row & (TT - 1);
    int tid = threadIdx.x;
    const u16* qr_ = qin + (size_t)row * CC;
    const u16* kr_ = kin + (size_t)row * CC;
    const u16* vr_ = vin + (size_t)row * CC;
    float sq = 0.f, ssq = 0.f, sk = 0.f, ssk = 0.f, sv = 0.f, ssv = 0.f;
    float xv[8];
    {
        u16x8 qv = *reinterpret_cast<const u16x8*>(qr_ + tid * 8);
        u16x8 kv = *reinterpret_cast<const u16x8*>(kr_ + tid * 8);
        u16x8 vv = *reinterpret_cast<const u16x8*>(vr_ + tid * 8);
        #pragma unroll
        for (int e = 0; e < 8; ++e) {
            float qf = bf2f(qv[e]), kf = bf2f(kv[e]);
            xv[e] = bf2f(vv[e]);
            sq += qf; ssq += qf * qf;
            sk += kf; ssk += kf * kf;
            sv += xv[e]; ssv += xv[e] * xv[e];
        }
    }
    #pragma unroll
    for (int o_ = 32; o_ > 0; o_ >>= 1) {
        sq += __shfl_xor(sq, o_); ssq += __shfl_xor(ssq, o_);
        sk += __shfl_xor(sk, o_); ssk += __shfl_xor(ssk, o_);
        sv += __shfl_xor(sv, o_); ssv += __shfl_xor(ssv, o_);
    }
    __shared__ float red[24];
    int wid = tid >> 6;
    if ((tid & 63) == 0) {
        red[wid] = sq; red[wid + 4] = ssq;
        red[wid + 8] = sk; red[wid + 12] = ssk;
        red[wid + 16] = sv; red[wid + 20] = ssv;
    }
    __syncthreads();
    sq  = red[0] + red[1] + red[2] + red[3];
    ssq = red[4] + red[5] + red[6] + red[7];
    sk  = red[8] + red[9] + red[10] + red[11];
    ssk = red[12] + red[13] + red[14] + red[15];
    sv  = red[16] + red[17] + red[18] + red[19];
    ssv = red[20] + red[21] + red[22] + red[23];
    float muq = sq * (1.0f / CC), vq = ssq * (1.0f / CC) - muq * muq, rq = rsqrtf(vq + 1e-5f);
    float muk = sk * (1.0f / CC), vk = ssk * (1.0f / CC) - muk * muk, rk = rsqrtf(vk + 1e-5f);
    float muv = sv * (1.0f / CC), vv_ = ssv * (1.0f / CC) - muv * muv, rv = rsqrtf(vv_ + 1e-5f);

    // V: straight LN, vectorized
    {
        fx4 g0 = *reinterpret_cast<const fx4*>(g_v + tid * 8);
        fx4 g1 = *reinterpret_cast<const fx4*>(g_v + tid * 8 + 4);
        fx4 b0 = *reinterpret_cast<const fx4*>(b_v + tid * 8);
        fx4 b1 = *reinterpret_cast<const fx4*>(b_v + tid * 8 + 4);
        u16x8 o8;
        #pragma unroll
        for (int e = 0; e < 4; ++e) o8[e]     = f2bf((xv[e] - muv) * rv * g0[e] + b0[e]);
        #pragma unroll
        for (int e = 0; e < 4; ++e) o8[e + 4] = f2bf((xv[e + 4] - muv) * rv * g1[e] + b1[e]);
        *reinterpret_cast<u16x8*>(vo + (size_t)row * CC + tid * 8) = o8;
    }

    // Q,K: LN + RoPE
    #pragma unroll
    for (int i = 0; i < 4; ++i) {
        int p = tid + i * 256;
        int h = p >> 5, d = p & 31;
        int c1 = h * 64 + d, c2 = c1 + 32;
        float cv = cosb[t * 32 + d], sv2 = sinb[t * 32 + d];
        float q1 = (bf2f(qr_[c1]) - muq) * rq * g_r[c1] + b_r[c1];
        float q2 = (bf2f(qr_[c2]) - muq) * rq * g_r[c2] + b_r[c2];
        qo[(size_t)row * CC + c1] = f2bf((q1 * cv - q2 * sv2) * 0.125f);
        qo[(size_t)row * CC + c2] = f2bf((q1 * sv2 + q2 * cv) * 0.125f);
        float k1 = (bf2f(kr_[c1]) - muk) * rk * g_k[c1] + b_k[c1];
        float k2 = (bf2f(kr_[c2]) - muk) * rk * g_k[c2] + b_k[c2];
        ko[(size_t)row * CC + c1] = f2bf(k1 * cv - k2 * sv2);
        ko[(size_t)row * CC + c2] = f2bf(k1 * sv2 + k2 * cv);
    }
}

// ---------------- V transpose: [b*TT+t][CC] -> [(b*HH+h)*KD+d][TT] ----------------
__global__ __launch_bounds__(256) void k_vtr(const u16* __restrict__ vin,
                                             u16* __restrict__ vout) {
    int t0 = blockIdx.x * 64, h = blockIdx.y, b = blockIdx.z;
    __shared__ u16 tile[64][72];
    int tid = threadIdx.x;
    #pragma unroll
    for (int u = 0; u < 2; ++u) {
        int g = tid + u * 256;
        int r = g >> 3, gc = g & 7;
        u16x8 vv = *reinterpret_cast<const u16x8*>(vin + (size_t)(b * TT + t0 + r) * CC + h * 64 + gc * 8);
        *reinterpret_cast<u16x8*>(&tile[r][gc * 8]) = vv;
    }
    __syncthreads();
    #pragma unroll
    for (int u = 0; u < 2; ++u) {
        int g = tid + u * 256;
        int d = g >> 3, tc = g & 7;
        u16x8 ov;
        #pragma unroll
        for (int e = 0; e < 8; ++e) ov[e] = tile[tc * 8 + e][d];
        *reinterpret_cast<u16x8*>(vout + ((size_t)(b * HH + h) * KD + d) * TT + t0 + tc * 8) = ov;
    }
}

// ---------------- MFMA bf16 flash attention: paired supertiles for load balance ----------------
// grid (TT/256, H, B) = (4,32,2); each block processes st = 7-bx then st = bx:
// (2(7-bx)+2) + (2bx+2) = 18 tiles for EVERY block -> perfect balance, 1 block/CU.
__global__ __launch_bounds__(512) void k_mattn4(const u16* __restrict__ q,
                                                const u16* __restrict__ k,
                                                const u16* __restrict__ vt,
                                                u16* __restrict__ o) {
    int h = blockIdx.y, b = blockIdx.z;
    __shared__ u16 Ks[3][64 * 64];
    __shared__ u16 Vs[3][64 * 64];
    __shared__ u16 Ps[8][16 * 64];
    int tid = threadIdx.x, lane = tid & 63, wave = tid >> 6;
    size_t bh = (size_t)b * TT * CC + (size_t)h * KD;
    const u16* vth = vt + (size_t)(b * HH + h) * KD * TT;
    int srow = (wave << 3) + (lane >> 3);
    int scol = ((lane & 7) ^ (srow & 7)) << 3;
    u16* pw = Ps[wave];
    int nst2 = (int)gridDim.x * 2;             // 8 supertiles

    #pragma unroll 1
    for (int pass = 0; pass < 2; ++pass) {
        int st = (pass == 0) ? (nst2 - 1 - (int)blockIdx.x) : (int)blockIdx.x;
        int qrow0 = st * 128 + wave * 16;
        int ktmax = 2 * st + 1;

        v8s qf[2];
        {
            const u16* qp = q + bh + (size_t)(qrow0 + (lane & 15)) * CC + (lane >> 4) * 8;
            qf[0] = *reinterpret_cast<const v8s*>(qp);
            qf[1] = *reinterpret_cast<const v8s*>(qp + 32);
        }

        float mstat[4], lstat[4];
        v4f oacc[4];
        #pragma unroll
        for (int j = 0; j < 4; ++j) { mstat[j] = -1e30f; lstat[j] = 0.f; }
        #pragma unroll
        for (int nd = 0; nd < 4; ++nd)
            #pragma unroll
            for (int e = 0; e < 4; ++e) oacc[nd][e] = 0.f;

        auto STAGE = [&](int slot, int kt) {
            gld16(k + bh + (size_t)(kt * 64 + srow) * CC + scol, &Ks[slot][wave * 512]);
            gld16(vth + (size_t)srow * TT + kt * 64 + scol, &Vs[slot][wave * 512]);
        };

        STAGE(0, 0);
        STAGE(1, 1);            // ktmax >= 1 always

        for (int kt = 0; kt <= ktmax; ++kt) {
            int cur = kt % 3;
            if (kt < ktmax) asm volatile("s_waitcnt vmcnt(2)" ::: "memory");
            else            asm volatile("s_waitcnt vmcnt(0)" ::: "memory");
            __builtin_amdgcn_s_barrier();
            __builtin_amdgcn_sched_barrier(0);
            if (kt + 2 <= ktmax) STAGE((kt + 2) % 3, kt + 2);

            if (kt * 64 <= qrow0 + 15) {
                const u16* KsC = Ks[cur];
                const u16* VsC = Vs[cur];

                v4f s[4];
                __builtin_amdgcn_s_setprio(1);
                #pragma unroll
                for (int ni = 0; ni < 4; ++ni) {
                    #pragma unroll
                    for (int e = 0; e < 4; ++e) s[ni][e] = 0.f;
                    #pragma unroll
                    for (int ks = 0; ks < 2; ++ks) {
                        int rl = ni * 16 + (lane & 15);
                        int kg = ks * 4 + (lane >> 4);
                        int swz = kg ^ (rl & 7);
                        v8s kf = *reinterpret_cast<const v8s*>(KsC + rl * 64 + swz * 8);
                        s[ni] = __builtin_amdgcn_mfma_f32_16x16x32_bf16(qf[ks], kf, s[ni], 0, 0, 0);
                    }
                }
                __builtin_amdgcn_s_setprio(0);
                if (kt * 64 + 63 > qrow0) {
                    int qr = qrow0 + (lane >> 4) * 4;
                    int kc = kt * 64 + (lane & 15);
                    #pragma unroll
                    for (int ni = 0; ni < 4; ++ni)
                        #pragma unroll
                        for (int j = 0; j < 4; ++j)
                            if (kc + ni * 16 > qr + j) s[ni][j] = -1e30f;
                }

                float alpha[4];
                #pragma unroll
                for (int j = 0; j < 4; ++j) {
                    float pm = fmaxf(fmaxf(s[0][j], s[1][j]), fmaxf(s[2][j], s[3][j]));
                    pm = fmaxf(pm, __shfl_xor(pm, 1));
                    pm = fmaxf(pm, __shfl_xor(pm, 2));
                    pm = fmaxf(pm, __shfl_xor(pm, 4));
                    pm = fmaxf(pm, __shfl_xor(pm, 8));
                    float mn = fmaxf(mstat[j], pm);
                    alpha[j] = __expf(mstat[j] - mn);
                    float rs = 0.f;
                    #pragma unroll
                    for (int ni = 0; ni < 4; ++ni) {
                        float p = __expf(s[ni][j] - mn);
                        s[ni][j] = p;
                        rs += p;
                    }
                    rs += __shfl_xor(rs, 1);
                    rs += __shfl_xor(rs, 2);
                    rs += __shfl_xor(rs, 4);
                    rs += __shfl_xor(rs, 8);
                    lstat[j] = lstat[j] * alpha[j] + rs;
                    mstat[j] = mn;
                }
                #pragma unroll
                for (int nd = 0; nd < 4; ++nd)
                    #pragma unroll
                    for (int j = 0; j < 4; ++j) oacc[nd][j] *= alpha[j];

                #pragma unroll
                for (int ni = 0; ni < 4; ++ni) {
                    int kc = (lane & 15) + ni * 16;
                    #pragma unroll
                    for (int j = 0; j < 4; ++j) {
                        int qr = (lane >> 4) * 4 + j;
                        int swz = (kc >> 3) ^ (qr & 7) ^ (qr >> 3);
                        pw[qr * 64 + swz * 8 + (kc & 7)] = f2bf(s[ni][j]);
                    }
                }

                v8s pf[2];
                #pragma unroll
                for (int ks = 0; ks < 2; ++ks) {
                    int prow = lane & 15;
                    int kg = ks * 4 + (lane >> 4);
                    int swz = kg ^ (prow & 7) ^ (prow >> 3);
                    pf[ks] = *reinterpret_cast<const v8s*>(pw + prow * 64 + swz * 8);
                }
                __builtin_amdgcn_s_setprio(1);
                #pragma unroll
                for (int nd = 0; nd < 4; ++nd) {
                    #pragma unroll
                    for (int ks = 0; ks < 2; ++ks) {
                        int vrow = nd * 16 + (lane & 15);
                        int vg = ks * 4 + (lane >> 4);
                        int vswz = vg ^ (vrow & 7);
                        v8s vf = *reinterpret_cast<const v8s*>(VsC + vrow * 64 + vswz * 8);
                        oacc[nd] = __builtin_amdgcn_mfma_f32_16x16x32_bf16(pf[ks], vf, oacc[nd], 0, 0, 0);
                    }
                }
                __builtin_amdgcn_s_setprio(0);
            }
        }

        #pragma unroll
        for (int j = 0; j < 4; ++j) {
            int qrow = qrow0 + (lane >> 4) * 4 + j;
            float inv = 1.0f / lstat[j];
            #pragma unroll
            for (int nd = 0; nd < 4; ++nd)
                o[bh + (size_t)qrow * CC + (lane & 15) + nd * 16] = f2bf(oacc[nd][j] * inv);
        }

        __syncthreads();   // all waves done with this pass's LDS before next pass restages
    }
}

extern "C" void kernel_launch(void* const* d_in, const int* in_sizes, int n_in,
                              void* d_out, int out_size, void* d_ws, size_t ws_size,
                              hipStream_t stream) {
    const float* x     = (const float*)d_in[0];
    const float* shift = (const float*)d_in[1];
    const float* maa_x = (const float*)d_in[2];
    const float* maa_r = (const float*)d_in[3];
    const float* maa_k = (const float*)d_in[4];
    const float* maa_v = (const float*)d_in[5];
    const float* w1    = (const float*)d_in[6];
    const float* w2    = (const float*)d_in[7];
    const float* Wq    = (const float*)d_in[8];
    const float* Wk    = (const float*)d_in[9];
    const float* Wv    = (const float*)d_in[10];
    const float* Wo    = (const float*)d_in[11];
    const float* g_r   = (const float*)d_in[12];
    const float* b_r   = (const float*)d_in[13];
    const float* g_k   = (const float*)d_in[14];
    const float* b_k   = (const float*)d_in[15];
    const float* g_v   = (const float*)d_in[16];
    const float* b_v   = (const float*)d_in[17];
    const float* g_x   = (const float*)d_in[18];
    const float* b_x   = (const float*)d_in[19];
    const float* cosb  = (const float*)d_in[20];
    const float* sinb  = (const float*)d_in[21];

    char* w = (char*)d_ws;
    const size_t WB = (size_t)BT * CC * 2;     // 8 MiB bf16 plane
    u16*   wtq  = (u16*)(w + 0 * WB);
    u16*   wtk  = (u16*)(w + 1 * WB);
    u16*   wtv  = (u16*)(w + 2 * WB);
    u16*   xqb  = (u16*)(w + 3 * WB);
    u16*   xkb  = (u16*)(w + 4 * WB);
    u16*   xvb  = (u16*)(w + 5 * WB);
    u16*   qb16 = (u16*)(w + 6 * WB);
    u16*   kb16 = (u16*)(w + 7 * WB);
    u16*   vb16 = (u16*)(w + 8 * WB);
    u16*   vtb  = (u16*)(w + 9 * WB);
    float* hp   = (float*)(w + 10 * WB);                 // 6.29 MB (8 partial slices)
    float* hb   = (float*)(w + 10 * WB + 0x600000);      // 786 KB
    u16*   w1t  = (u16*)(w + 10 * WB + 0x700000);        // 384 KB
    u16*   wto  = (u16*)(w + 11 * WB);
    // aliases over consumed planes:
    u16*   qbb = (u16*)(w + 3 * WB);           // roped Q over xqb
    u16*   kbb = (u16*)(w + 4 * WB);           // roped K over xkb
    u16*   vbb = (u16*)(w + 5 * WB);           // LN'd V over xvb
    u16*   ob  = (u16*)(w + 6 * WB);           // attn out over qb16
    u16*   oln = (u16*)(w + 7 * WB);           // LN(attn) over kb16
    float* out = (float*)d_out;

    k_tconv5<<<dim3(32, 32, 5), 256, 0, stream>>>(Wq, Wk, Wv, Wo, w1,
                                                  wtq, wtk, wtv, wto, w1t);

    k_lgemm<<<dim3(BT / 16, 8), 128, 0, stream>>>(x, shift, maa_x, w1t, hp);
    k_lred<<<BT * 96 / 1024, 256, 0, stream>>>(hp, hb);
    k_mix2<<<dim3(32, 32), 256, 0, stream>>>(x, shift, hb, w2, maa_r, maa_k, maa_v,
                                             xqb, xkb, xvb);

    k_gemm_qkv<<<dim3(256, 3), 256, 0, stream>>>(xqb, xkb, xvb, wtq, wtk, wtv,
                                                 qb16, kb16, vb16);

    k_lnrope3<<<BT, 256, 0, stream>>>(qb16, kb16, vb16, qbb, kbb, vbb,
                                      g_r, b_r, g_k, b_k, g_v, b_v, cosb, sinb);
    k_vtr<<<dim3(TT / 64, HH, BB), 256, 0, stream>>>(vbb, vtb);

    k_mattn4<<<dim3(TT / 256, HH, BB), 512, 0, stream>>>(qbb, kbb, vtb, ob);

    k_ln_bb<<<BT, 256, 0, stream>>>(oln, ob, g_x, b_x);
    k_gemm1<<<256, 256, 0, stream>>>(oln, wto, out);
}

// Round 14
// 214.981 us; speedup vs baseline: 1.0630x; 1.0134x over previous
//
#include <hip/hip_runtime.h>
#include <math.h>

static constexpr int BB = 2;
static constexpr int TT = 1024;
static constexpr int CC = 2048;
static constexpr int HH = 32;
static constexpr int KD = 64;
static constexpr int BT = BB * TT;

typedef short   v8s  __attribute__((ext_vector_type(8)));
typedef float   v4f  __attribute__((ext_vector_type(4)));
typedef unsigned short u16;
typedef u16     u16x8 __attribute__((ext_vector_type(8)));
typedef u16     u16x4 __attribute__((ext_vector_type(4)));
typedef float   fx4  __attribute__((ext_vector_type(4)));

__device__ __forceinline__ u16 f2bf(float f) {
    unsigned u = __builtin_bit_cast(unsigned, f);
    u = u + 0x7FFFu + ((u >> 16) & 1u);   // RNE
    return (u16)(u >> 16);
}
__device__ __forceinline__ float bf2f(u16 v) {
    return __builtin_bit_cast(float, ((unsigned)v) << 16);
}

// async global->LDS, 16B per lane; dest is wave-uniform base + lane*16
__device__ __forceinline__ void gld16(const u16* g, u16* l) {
    __builtin_amdgcn_global_load_lds(
        (const __attribute__((address_space(1))) void*)g,
        (__attribute__((address_space(3))) void*)l, 16, 0, 0);
}

__device__ __forceinline__ void cstore(float* p, float v) { *p = v; }
__device__ __forceinline__ void cstore(u16* p, float v)   { *p = f2bf(v); }

// XCD chunk swizzle: 256 blocks -> 16x16 tile grid, each XCD a 4x8 chunk
__device__ __forceinline__ void xcd_map(int bid, int& bx, int& by) {
    int i = bid & 7;
    int j = bid >> 3;
    bx = (i & 3) * 4 + (j & 3);
    by = (i >> 2) * 8 + (j >> 2);
}

// ---------------- transpose-convert weights (z<4) + w1 (z==4) ----------------
__global__ __launch_bounds__(256) void k_tconv5(const float* __restrict__ W0,
                                                const float* __restrict__ W1,
                                                const float* __restrict__ W2,
                                                const float* __restrict__ W3,
                                                const float* __restrict__ w1,
                                                u16* __restrict__ T0, u16* __restrict__ T1,
                                                u16* __restrict__ T2, u16* __restrict__ T3,
                                                u16* __restrict__ w1t) {
    __shared__ float tile[64][97];
    int tid = threadIdx.x;
    int z = blockIdx.z;
    if (z == 4) {                              // w1 f32 [2048][96] -> bf16 [96][2048]
        if (blockIdx.y != 0) return;
        int kb = blockIdx.x * 64;
        for (int i = tid; i < 64 * 96; i += 256) {
            int r = i / 96, c = i - r * 96;
            tile[r][c] = w1[(size_t)(kb + r) * 96 + c];
        }
        __syncthreads();
        for (int i = tid; i < 96 * 64; i += 256) {
            int n = i >> 6, k = i & 63;
            w1t[(size_t)n * CC + kb + k] = f2bf(tile[k][n]);
        }
        return;
    }
    const float* W = (z == 0) ? W0 : (z == 1) ? W1 : (z == 2) ? W2 : W3;
    u16* Wt = (z == 0) ? T0 : (z == 1) ? T1 : (z == 2) ? T2 : T3;
    int nb = blockIdx.x * 64, kb = blockIdx.y * 64;
    for (int i = tid; i < 4096; i += 256) {
        int r = i >> 6, c = i & 63;
        tile[r][c] = W[(size_t)(kb + r) * CC + nb + c];
    }
    __syncthreads();
    for (int i = tid; i < 4096; i += 256) {
        int r = i >> 6, c = i & 63;
        Wt[(size_t)(nb + r) * CC + kb + c] = f2bf(tile[c][r]);
    }
}

// ---------------- K1 as MFMA GEMM, K-split x8 ----------------
__global__ __launch_bounds__(128) void k_lgemm(const float* __restrict__ x,
                                               const float* __restrict__ shift,
                                               const float* __restrict__ maa_x,
                                               const u16* __restrict__ w1t,
                                               float* __restrict__ hp) {
    __shared__ u16 As[16 * 64];
    __shared__ u16 Bs[96 * 64];
    int tid = threadIdx.x, lane = tid & 63, wave = tid >> 6;
    int brow = blockIdx.x * 16;
    int kbeg = blockIdx.y * 256;

    int ar = tid >> 3, ag = tid & 7;
    int grow = brow + ar;
    int t = grow & (TT - 1), b = grow >> 10;
    const float* xr = x + (size_t)grow * CC;
    const float* xp = (t == 0) ? (shift + (size_t)b * CC) : (xr - CC);
    u16* adst = As + ar * 64 + ((ag ^ (ar & 7)) * 8);

    v4f acc[3];
    #pragma unroll
    for (int ni = 0; ni < 3; ++ni)
        #pragma unroll
        for (int e = 0; e < 4; ++e) acc[ni][e] = 0.f;

    for (int k0 = kbeg; k0 < kbeg + 256; k0 += 64) {
        __syncthreads();
        #pragma unroll
        for (int u = 0; u < 6; ++u) {
            int r = (wave * 6 + u) * 8 + (lane >> 3);
            int sc = ((lane & 7) ^ (r & 7)) * 8;
            gld16(w1t + (size_t)r * CC + k0 + sc, Bs + (wave * 6 + u) * 512);
        }
        {
            int kb_ = k0 + ag * 8;
            fx4 x0 = *reinterpret_cast<const fx4*>(xr + kb_);
            fx4 x1 = *reinterpret_cast<const fx4*>(xr + kb_ + 4);
            fx4 p0 = *reinterpret_cast<const fx4*>(xp + kb_);
            fx4 p1 = *reinterpret_cast<const fx4*>(xp + kb_ + 4);
            fx4 m0 = *reinterpret_cast<const fx4*>(maa_x + kb_);
            fx4 m1 = *reinterpret_cast<const fx4*>(maa_x + kb_ + 4);
            fx4 r0 = x0 + (p0 - x0) * m0;
            fx4 r1 = x1 + (p1 - x1) * m1;
            u16x8 a8;
            #pragma unroll
            for (int e = 0; e < 4; ++e) { a8[e] = f2bf(r0[e]); a8[e + 4] = f2bf(r1[e]); }
            *reinterpret_cast<u16x8*>(adst) = a8;
        }
        __syncthreads();

        #pragma unroll
        for (int ks = 0; ks < 2; ++ks) {
            int kg = ks * 4 + (lane >> 4);
            int rlA = lane & 15;
            v8s af = *reinterpret_cast<const v8s*>(As + rlA * 64 + ((kg ^ (rlA & 7)) * 8));
            #pragma unroll
            for (int ni = 0; ni < 3; ++ni) {
                int rlB = wave * 48 + ni * 16 + (lane & 15);
                v8s bf = *reinterpret_cast<const v8s*>(Bs + rlB * 64 + ((kg ^ (rlB & 7)) * 8));
                acc[ni] = __builtin_amdgcn_mfma_f32_16x16x32_bf16(af, bf, acc[ni], 0, 0, 0);
            }
        }
    }

    float* hpk = hp + (size_t)blockIdx.y * BT * 96;
    #pragma unroll
    for (int ni = 0; ni < 3; ++ni) {
        int col = wave * 48 + ni * 16 + (lane & 15);
        #pragma unroll
        for (int j = 0; j < 4; ++j) {
            int row = brow + (lane >> 4) * 4 + j;
            hpk[(size_t)row * 96 + col] = acc[ni][j];
        }
    }
}

// ---------------- reduce 8 partials + tanh ----------------
__global__ __launch_bounds__(256) void k_lred(const float* __restrict__ hp,
                                              float* __restrict__ h) {
    int i = (blockIdx.x * 256 + threadIdx.x) * 4;
    const size_t S = (size_t)BT * 96;
    fx4 s = *reinterpret_cast<const fx4*>(hp + i);
    #pragma unroll
    for (int p = 1; p < 8; ++p)
        s += *reinterpret_cast<const fx4*>(hp + (size_t)p * S + i);
    fx4 o;
    #pragma unroll
    for (int e = 0; e < 4; ++e) o[e] = tanhf(s[e]);
    *reinterpret_cast<fx4*>(h + i) = o;
}

// ---------------- K2: tiled mix ----------------
__global__ __launch_bounds__(256) void k_mix2(const float* __restrict__ x,
                                              const float* __restrict__ shift,
                                              const float* __restrict__ h_in,
                                              const float* __restrict__ w2,
                                              const float* __restrict__ maa_r,
                                              const float* __restrict__ maa_k,
                                              const float* __restrict__ maa_v,
                                              u16* __restrict__ oq,
                                              u16* __restrict__ ok,
                                              u16* __restrict__ ov) {
    __shared__ float w2s[96][64];
    __shared__ float hs[64][100];
    int tid = threadIdx.x;
    int c0 = blockIdx.x * 64, r0 = blockIdx.y * 64;
    for (int i = tid; i < 96 * 64; i += 256) {
        int r = i >> 6, c = i & 63;
        w2s[r][c] = w2[(size_t)r * CC + c0 + c];
    }
    for (int i = tid; i < 64 * 96; i += 256) {
        int r = i / 96, jj = i - r * 96;
        hs[r][jj] = h_in[(size_t)(r0 + r) * 96 + jj];
    }
    __syncthreads();

    int cq = tid & 15, rg = tid >> 4;
    int c = c0 + cq * 4;
    fx4 acc[4][3];
    #pragma unroll
    for (int r = 0; r < 4; ++r)
        #pragma unroll
        for (int l = 0; l < 3; ++l)
            #pragma unroll
            for (int e = 0; e < 4; ++e) acc[r][l][e] = 0.f;

    #pragma unroll 2
    for (int i4 = 0; i4 < 8; ++i4) {
        fx4 hv[4][3];
        #pragma unroll
        for (int r = 0; r < 4; ++r) {
            int row = rg * 4 + r;
            hv[r][0] = *reinterpret_cast<const fx4*>(&hs[row][i4 * 4]);
            hv[r][1] = *reinterpret_cast<const fx4*>(&hs[row][32 + i4 * 4]);
            hv[r][2] = *reinterpret_cast<const fx4*>(&hs[row][64 + i4 * 4]);
        }
        #pragma unroll
        for (int e = 0; e < 4; ++e) {
            int i = i4 * 4 + e;
            fx4 w0 = *reinterpret_cast<const fx4*>(&w2s[i][cq * 4]);
            fx4 w1v = *reinterpret_cast<const fx4*>(&w2s[32 + i][cq * 4]);
            fx4 w2v = *reinterpret_cast<const fx4*>(&w2s[64 + i][cq * 4]);
            #pragma unroll
            for (int r = 0; r < 4; ++r) {
                acc[r][0] += hv[r][0][e] * w0;
                acc[r][1] += hv[r][1][e] * w1v;
                acc[r][2] += hv[r][2][e] * w2v;
            }
        }
    }

    fx4 m_r = *reinterpret_cast<const fx4*>(maa_r + c);
    fx4 m_k = *reinterpret_cast<const fx4*>(maa_k + c);
    fx4 m_v = *reinterpret_cast<const fx4*>(maa_v + c);
    #pragma unroll
    for (int r = 0; r < 4; ++r) {
        int grow = r0 + rg * 4 + r;
        int t = grow & (TT - 1), b = grow >> 10;
        const float* xr = x + (size_t)grow * CC;
        const float* xp = (t == 0) ? (shift + (size_t)b * CC) : (xr - CC);
        fx4 xv = *reinterpret_cast<const fx4*>(xr + c);
        fx4 pv = *reinterpret_cast<const fx4*>(xp + c);
        fx4 dx = pv - xv;
        fx4 rq = xv + dx * (m_r + acc[r][0]);
        fx4 rk = xv + dx * (m_k + acc[r][1]);
        fx4 rv = xv + dx * (m_v + acc[r][2]);
        u16x4 pq, pk, pvv;
        #pragma unroll
        for (int e = 0; e < 4; ++e) { pq[e] = f2bf(rq[e]); pk[e] = f2bf(rk[e]); pvv[e] = f2bf(rv[e]); }
        size_t o = (size_t)grow * CC + c;
        *reinterpret_cast<u16x4*>(oq + o) = pq;
        *reinterpret_cast<u16x4*>(ok + o) = pk;
        *reinterpret_cast<u16x4*>(ov + o) = pvv;
    }
}

// ---------------- MFMA bf16 GEMM body (global_load_lds staging) ----------------
template <typename CT>
__device__ __forceinline__ void gemm_body(const u16* __restrict__ A,
                                          const u16* __restrict__ Bt,
                                          CT* __restrict__ C,
                                          int bm, int bn) {
    constexpr int Kd = 2048, Nd = 2048;
    __shared__ u16 As[128 * 64];
    __shared__ u16 Bs[128 * 64];
    int tid = threadIdx.x;
    int lane = tid & 63, wave = tid >> 6;
    int wr = wave >> 1, wc = wave & 1;

    int srow[4], scol[4];
    #pragma unroll
    for (int q = 0; q < 4; ++q) {
        int e = q * 2048 + wave * 512 + lane * 8;
        int row = e >> 6;
        srow[q] = row;
        scol[q] = ((lane & 7) ^ (row & 7)) * 8;
    }

    v4f acc[4][4];
    #pragma unroll
    for (int i = 0; i < 4; ++i)
        #pragma unroll
        for (int j = 0; j < 4; ++j)
            #pragma unroll
            for (int e = 0; e < 4; ++e) acc[i][j][e] = 0.f;

    for (int k0 = 0; k0 < Kd; k0 += 64) {
        __syncthreads();
        #pragma unroll
        for (int q = 0; q < 4; ++q)
            gld16(A + (size_t)(bm + srow[q]) * Kd + k0 + scol[q], As + q * 2048 + wave * 512);
        #pragma unroll
        for (int q = 0; q < 4; ++q)
            gld16(Bt + (size_t)(bn + srow[q]) * Kd + k0 + scol[q], Bs + q * 2048 + wave * 512);
        __syncthreads();
        #pragma unroll
        for (int ks = 0; ks < 2; ++ks) {
            int kg = ks * 4 + (lane >> 4);
            v8s af[4], bf[4];
            #pragma unroll
            for (int mi = 0; mi < 4; ++mi) {
                int rl = wr * 64 + mi * 16 + (lane & 15);
                af[mi] = *reinterpret_cast<const v8s*>(As + rl * 64 + ((kg ^ (rl & 7)) * 8));
            }
            #pragma unroll
            for (int ni = 0; ni < 4; ++ni) {
                int rl = wc * 64 + ni * 16 + (lane & 15);
                bf[ni] = *reinterpret_cast<const v8s*>(Bs + rl * 64 + ((kg ^ (rl & 7)) * 8));
            }
            #pragma unroll
            for (int mi = 0; mi < 4; ++mi)
                #pragma unroll
                for (int ni = 0; ni < 4; ++ni)
                    acc[mi][ni] = __builtin_amdgcn_mfma_f32_16x16x32_bf16(af[mi], bf[ni], acc[mi][ni], 0, 0, 0);
        }
    }

    int cr = (lane >> 4) * 4;
    int ccol = lane & 15;
    #pragma unroll
    for (int mi = 0; mi < 4; ++mi)
        #pragma unroll
        for (int ni = 0; ni < 4; ++ni) {
            CT* cp = C + (size_t)(bm + wr * 64 + mi * 16 + cr) * Nd + bn + wc * 64 + ni * 16 + ccol;
            #pragma unroll
            for (int j = 0; j < 4; ++j) cstore(cp + (size_t)j * Nd, acc[mi][ni][j]);
        }
}

__global__ __launch_bounds__(256) void k_gemm_qkv(const u16* A0, const u16* A1, const u16* A2,
                                                  const u16* B0, const u16* B1, const u16* B2,
                                                  u16* C0, u16* C1, u16* C2) {
    int z = blockIdx.y;
    const u16* A = (z == 0) ? A0 : (z == 1) ? A1 : A2;
    const u16* B = (z == 0) ? B0 : (z == 1) ? B1 : B2;
    u16* C = (z == 0) ? C0 : (z == 1) ? C1 : C2;
    int bx, by;
    xcd_map(blockIdx.x, bx, by);
    gemm_body<u16>(A, B, C, by * 128, bx * 128);
}

__global__ __launch_bounds__(256) void k_gemm1(const u16* __restrict__ A,
                                               const u16* __restrict__ Bt,
                                               float* __restrict__ C) {
    int bx, by;
    xcd_map(blockIdx.x, bx, by);
    gemm_body<float>(A, Bt, C, by * 128, bx * 128);
}

// ---------------- LayerNorm (bf16 in, bf16 out) ----------------
__global__ __launch_bounds__(256) void k_ln_bb(u16* __restrict__ y, const u16* __restrict__ xin,
                                               const float* __restrict__ g, const float* __restrict__ bb) {
    int row = blockIdx.x;
    const u16* xr = xin + (size_t)row * CC;
    int tid = threadIdx.x;
    u16x8 v8 = *reinterpret_cast<const u16x8*>(xr + tid * 8);
    float xv[8];
    float s = 0.f, ss = 0.f;
    #pragma unroll
    for (int e = 0; e < 8; ++e) { xv[e] = bf2f(v8[e]); s += xv[e]; ss += xv[e] * xv[e]; }
    #pragma unroll
    for (int o = 32; o > 0; o >>= 1) { s += __shfl_xor(s, o); ss += __shfl_xor(ss, o); }
    __shared__ float red[8];
    int wid = tid >> 6;
    if ((tid & 63) == 0) { red[wid] = s; red[wid + 4] = ss; }
    __syncthreads();
    s  = red[0] + red[1] + red[2] + red[3];
    ss = red[4] + red[5] + red[6] + red[7];
    float mu  = s * (1.0f / CC);
    float var = ss * (1.0f / CC) - mu * mu;
    float rsg = rsqrtf(var + 1e-5f);
    fx4 g0 = *reinterpret_cast<const fx4*>(g + tid * 8);
    fx4 g1 = *reinterpret_cast<const fx4*>(g + tid * 8 + 4);
    fx4 b0 = *reinterpret_cast<const fx4*>(bb + tid * 8);
    fx4 b1 = *reinterpret_cast<const fx4*>(bb + tid * 8 + 4);
    u16x8 o8;
    #pragma unroll
    for (int e = 0; e < 4; ++e) o8[e]     = f2bf((xv[e] - mu) * rsg * g0[e] + b0[e]);
    #pragma unroll
    for (int e = 0; e < 4; ++e) o8[e + 4] = f2bf((xv[e + 4] - mu) * rsg * g1[e] + b1[e]);
    *reinterpret_cast<u16x8*>(y + (size_t)row * CC + tid * 8) = o8;
}

// ---------------- fused LN(q)+LN(k)+LN(v)+RoPE(q,k), bf16->bf16 (q pre-scaled 1/8) ----------------
__global__ __launch_bounds__(256) void k_lnrope3(const u16* __restrict__ qin,
                                                 const u16* __restrict__ kin,
                                                 const u16* __restrict__ vin,
                                                 u16* __restrict__ qo, u16* __restrict__ ko,
                                                 u16* __restrict__ vo,
                                                 const float* __restrict__ g_r, const float* __restrict__ b_r,
                                                 const float* __restrict__ g_k, const float* __restrict__ b_k,
                                                 const float* __restrict__ g_v, const float* __restrict__ b_v,
                                                 const float* __restrict__ cosb, const float* __restrict__ sinb) {
    int row = blockIdx.x;
    int t = row & (TT - 1);
    int tid = threadIdx.x;
    const u16* qr_ = qin + (size_t)row * CC;
    const u16* kr_ = kin + (size_t)row * CC;
    const u16* vr_ = vin + (size_t)row * CC;
    float sq = 0.f, ssq = 0.f, sk = 0.f, ssk = 0.f, sv = 0.f, ssv = 0.f;
    float xv[8];
    {
        u16x8 qv = *reinterpret_cast<const u16x8*>(qr_ + tid * 8);
        u16x8 kv = *reinterpret_cast<const u16x8*>(kr_ + tid * 8);
        u16x8 vv = *reinterpret_cast<const u16x8*>(vr_ + tid * 8);
        #pragma unroll
        for (int e = 0; e < 8; ++e) {
            float qf = bf2f(qv[e]), kf = bf2f(kv[e]);
            xv[e] = bf2f(vv[e]);
            sq += qf; ssq += qf * qf;
            sk += kf; ssk += kf * kf;
            sv += xv[e]; ssv += xv[e] * xv[e];
        }
    }
    #pragma unroll
    for (int o_ = 32; o_ > 0; o_ >>= 1) {
        sq += __shfl_xor(sq, o_); ssq += __shfl_xor(ssq, o_);
        sk += __shfl_xor(sk, o_); ssk += __shfl_xor(ssk, o_);
        sv += __shfl_xor(sv, o_); ssv += __shfl_xor(ssv, o_);
    }
    __shared__ float red[24];
    int wid = tid >> 6;
    if ((tid & 63) == 0) {
        red[wid] = sq; red[wid + 4] = ssq;
        red[wid + 8] = sk; red[wid + 12] = ssk;
        red[wid + 16] = sv; red[wid + 20] = ssv;
    }
    __syncthreads();
    sq  = red[0] + red[1] + red[2] + red[3];
    ssq = red[4] + red[5] + red[6] + red[7];
    sk  = red[8] + red[9] + red[10] + red[11];
    ssk = red[12] + red[13] + red[14] + red[15];
    sv  = red[16] + red[17] + red[18] + red[19];
    ssv = red[20] + red[21] + red[22] + red[23];
    float muq = sq * (1.0f / CC), vq = ssq * (1.0f / CC) - muq * muq, rq = rsqrtf(vq + 1e-5f);
    float muk = sk * (1.0f / CC), vk = ssk * (1.0f / CC) - muk * muk, rk = rsqrtf(vk + 1e-5f);
    float muv = sv * (1.0f / CC), vv_ = ssv * (1.0f / CC) - muv * muv, rv = rsqrtf(vv_ + 1e-5f);

    // V: straight LN, vectorized
    {
        fx4 g0 = *reinterpret_cast<const fx4*>(g_v + tid * 8);
        fx4 g1 = *reinterpret_cast<const fx4*>(g_v + tid * 8 + 4);
        fx4 b0 = *reinterpret_cast<const fx4*>(b_v + tid * 8);
        fx4 b1 = *reinterpret_cast<const fx4*>(b_v + tid * 8 + 4);
        u16x8 o8;
        #pragma unroll
        for (int e = 0; e < 4; ++e) o8[e]     = f2bf((xv[e] - muv) * rv * g0[e] + b0[e]);
        #pragma unroll
        for (int e = 0; e < 4; ++e) o8[e + 4] = f2bf((xv[e + 4] - muv) * rv * g1[e] + b1[e]);
        *reinterpret_cast<u16x8*>(vo + (size_t)row * CC + tid * 8) = o8;
    }

    // Q,K: LN + RoPE
    #pragma unroll
    for (int i = 0; i < 4; ++i) {
        int p = tid + i * 256;
        int h = p >> 5, d = p & 31;
        int c1 = h * 64 + d, c2 = c1 + 32;
        float cv = cosb[t * 32 + d], sv2 = sinb[t * 32 + d];
        float q1 = (bf2f(qr_[c1]) - muq) * rq * g_r[c1] + b_r[c1];
        float q2 = (bf2f(qr_[c2]) - muq) * rq * g_r[c2] + b_r[c2];
        qo[(size_t)row * CC + c1] = f2bf((q1 * cv - q2 * sv2) * 0.125f);
        qo[(size_t)row * CC + c2] = f2bf((q1 * sv2 + q2 * cv) * 0.125f);
        float k1 = (bf2f(kr_[c1]) - muk) * rk * g_k[c1] + b_k[c1];
        float k2 = (bf2f(kr_[c2]) - muk) * rk * g_k[c2] + b_k[c2];
        ko[(size_t)row * CC + c1] = f2bf(k1 * cv - k2 * sv2);
        ko[(size_t)row * CC + c2] = f2bf(k1 * sv2 + k2 * cv);
    }
}

// ---------------- V transpose: [b*TT+t][CC] -> [(b*HH+h)*KD+d][TT] ----------------
__global__ __launch_bounds__(256) void k_vtr(const u16* __restrict__ vin,
                                             u16* __restrict__ vout) {
    int t0 = blockIdx.x * 64, h = blockIdx.y, b = blockIdx.z;
    __shared__ u16 tile[64][72];
    int tid = threadIdx.x;
    #pragma unroll
    for (int u = 0; u < 2; ++u) {
        int g = tid + u * 256;
        int r = g >> 3, gc = g & 7;
        u16x8 vv = *reinterpret_cast<const u16x8*>(vin + (size_t)(b * TT + t0 + r) * CC + h * 64 + gc * 8);
        *reinterpret_cast<u16x8*>(&tile[r][gc * 8]) = vv;
    }
    __syncthreads();
    #pragma unroll
    for (int u = 0; u < 2; ++u) {
        int g = tid + u * 256;
        int d = g >> 3, tc = g & 7;
        u16x8 ov;
        #pragma unroll
        for (int e = 0; e < 8; ++e) ov[e] = tile[tc * 8 + e][d];
        *reinterpret_cast<u16x8*>(vout + ((size_t)(b * HH + h) * KD + d) * TT + t0 + tc * 8) = ov;
    }
}

// ---------------- MFMA bf16 flash attention: paired supertiles + 2-tile groups ----------------
// grid (TT/256, H, B) = (4,32,2); block does st = 7-bx then st = bx (18 tiles each).
// Tiles processed in GROUPS of 2 per barrier (tiles/pass = 2st+2, always even -> st+1 groups).
// Triple-buffered 2-tile slots; single barrier per group; counted vmcnt(4)/vmcnt(0).
__global__ __launch_bounds__(512) void k_mattn5(const u16* __restrict__ q,
                                                const u16* __restrict__ k,
                                                const u16* __restrict__ vt,
                                                u16* __restrict__ o) {
    int h = blockIdx.y, b = blockIdx.z;
    __shared__ u16 Ks[3][2][64 * 64];
    __shared__ u16 Vs[3][2][64 * 64];
    __shared__ u16 Ps[8][16 * 64];
    int tid = threadIdx.x, lane = tid & 63, wave = tid >> 6;
    size_t bh = (size_t)b * TT * CC + (size_t)h * KD;
    const u16* vth = vt + (size_t)(b * HH + h) * KD * TT;
    int srow = (wave << 3) + (lane >> 3);
    int scol = ((lane & 7) ^ (srow & 7)) << 3;
    u16* pw = Ps[wave];
    int nst2 = (int)gridDim.x * 2;             // 8 supertiles

    #pragma unroll 1
    for (int pass = 0; pass < 2; ++pass) {
        int st = (pass == 0) ? (nst2 - 1 - (int)blockIdx.x) : (int)blockIdx.x;
        int qrow0 = st * 128 + wave * 16;
        int ngrp = st + 1;                     // groups of 2 tiles

        v8s qf[2];
        {
            const u16* qp = q + bh + (size_t)(qrow0 + (lane & 15)) * CC + (lane >> 4) * 8;
            qf[0] = *reinterpret_cast<const v8s*>(qp);
            qf[1] = *reinterpret_cast<const v8s*>(qp + 32);
        }

        float mstat[4], lstat[4];
        v4f oacc[4];
        #pragma unroll
        for (int j = 0; j < 4; ++j) { mstat[j] = -1e30f; lstat[j] = 0.f; }
        #pragma unroll
        for (int nd = 0; nd < 4; ++nd)
            #pragma unroll
            for (int e = 0; e < 4; ++e) oacc[nd][e] = 0.f;

        auto STAGE2 = [&](int slot, int g) {   // stage tiles 2g, 2g+1 (4 loads/thread)
            int kt0 = 2 * g;
            gld16(k + bh + (size_t)(kt0 * 64 + srow) * CC + scol, &Ks[slot][0][wave * 512]);
            gld16(vth + (size_t)srow * TT + kt0 * 64 + scol, &Vs[slot][0][wave * 512]);
            gld16(k + bh + (size_t)((kt0 + 1) * 64 + srow) * CC + scol, &Ks[slot][1][wave * 512]);
            gld16(vth + (size_t)srow * TT + (kt0 + 1) * 64 + scol, &Vs[slot][1][wave * 512]);
        };

        STAGE2(0, 0);
        if (ngrp > 1) STAGE2(1, 1);

        for (int g = 0; g < ngrp; ++g) {
            int cur = g % 3;
            if (g + 1 < ngrp) asm volatile("s_waitcnt vmcnt(4)" ::: "memory");
            else              asm volatile("s_waitcnt vmcnt(0)" ::: "memory");
            __builtin_amdgcn_s_barrier();      // group g landed AND all waves done with g-1
            __builtin_amdgcn_sched_barrier(0);
            if (g + 2 < ngrp) STAGE2((g + 2) % 3, g + 2);   // slot freed by group g-1

            #pragma unroll
            for (int sub = 0; sub < 2; ++sub) {
                int kt = 2 * g + sub;
                if (kt * 64 > qrow0 + 15) continue;   // fully masked for this wave
                const u16* KsC = Ks[cur][sub];
                const u16* VsC = Vs[cur][sub];

                v4f s[4];
                __builtin_amdgcn_s_setprio(1);
                #pragma unroll
                for (int ni = 0; ni < 4; ++ni) {
                    #pragma unroll
                    for (int e = 0; e < 4; ++e) s[ni][e] = 0.f;
                    #pragma unroll
                    for (int ks = 0; ks < 2; ++ks) {
                        int rl = ni * 16 + (lane & 15);
                        int kg = ks * 4 + (lane >> 4);
                        int swz = kg ^ (rl & 7);
                        v8s kf = *reinterpret_cast<const v8s*>(KsC + rl * 64 + swz * 8);
                        s[ni] = __builtin_amdgcn_mfma_f32_16x16x32_bf16(qf[ks], kf, s[ni], 0, 0, 0);
                    }
                }
                __builtin_amdgcn_s_setprio(0);
                if (kt * 64 + 63 > qrow0) {
                    int qr = qrow0 + (lane >> 4) * 4;
                    int kc = kt * 64 + (lane & 15);
                    #pragma unroll
                    for (int ni = 0; ni < 4; ++ni)
                        #pragma unroll
                        for (int j = 0; j < 4; ++j)
                            if (kc + ni * 16 > qr + j) s[ni][j] = -1e30f;
                }

                float alpha[4];
                #pragma unroll
                for (int j = 0; j < 4; ++j) {
                    float pm = fmaxf(fmaxf(s[0][j], s[1][j]), fmaxf(s[2][j], s[3][j]));
                    pm = fmaxf(pm, __shfl_xor(pm, 1));
                    pm = fmaxf(pm, __shfl_xor(pm, 2));
                    pm = fmaxf(pm, __shfl_xor(pm, 4));
                    pm = fmaxf(pm, __shfl_xor(pm, 8));
                    float mn = fmaxf(mstat[j], pm);
                    alpha[j] = __expf(mstat[j] - mn);
                    float rs = 0.f;
                    #pragma unroll
                    for (int ni = 0; ni < 4; ++ni) {
                        float p = __expf(s[ni][j] - mn);
                        s[ni][j] = p;
                        rs += p;
                    }
                    rs += __shfl_xor(rs, 1);
                    rs += __shfl_xor(rs, 2);
                    rs += __shfl_xor(rs, 4);
                    rs += __shfl_xor(rs, 8);
                    lstat[j] = lstat[j] * alpha[j] + rs;
                    mstat[j] = mn;
                }
                #pragma unroll
                for (int nd = 0; nd < 4; ++nd)
                    #pragma unroll
                    for (int j = 0; j < 4; ++j) oacc[nd][j] *= alpha[j];

                #pragma unroll
                for (int ni = 0; ni < 4; ++ni) {
                    int kc = (lane & 15) + ni * 16;
                    #pragma unroll
                    for (int j = 0; j < 4; ++j) {
                        int qr = (lane >> 4) * 4 + j;
                        int swz = (kc >> 3) ^ (qr & 7) ^ (qr >> 3);
                        pw[qr * 64 + swz * 8 + (kc & 7)] = f2bf(s[ni][j]);
                    }
                }

                v8s pf[2];
                #pragma unroll
                for (int ks = 0; ks < 2; ++ks) {
                    int prow = lane & 15;
                    int kg = ks * 4 + (lane >> 4);
                    int swz = kg ^ (prow & 7) ^ (prow >> 3);
                    pf[ks] = *reinterpret_cast<const v8s*>(pw + prow * 64 + swz * 8);
                }
                __builtin_amdgcn_s_setprio(1);
                #pragma unroll
                for (int nd = 0; nd < 4; ++nd) {
                    #pragma unroll
                    for (int ks = 0; ks < 2; ++ks) {
                        int vrow = nd * 16 + (lane & 15);
                        int vg = ks * 4 + (lane >> 4);
                        int vswz = vg ^ (vrow & 7);
                        v8s vf = *reinterpret_cast<const v8s*>(VsC + vrow * 64 + vswz * 8);
                        oacc[nd] = __builtin_amdgcn_mfma_f32_16x16x32_bf16(pf[ks], vf, oacc[nd], 0, 0, 0);
                    }
                }
                __builtin_amdgcn_s_setprio(0);
            }
        }

        #pragma unroll
        for (int j = 0; j < 4; ++j) {
            int qrow = qrow0 + (lane >> 4) * 4 + j;
            float inv = 1.0f / lstat[j];
            #pragma unroll
            for (int nd = 0; nd < 4; ++nd)
                o[bh + (size_t)qrow * CC + (lane & 15) + nd * 16] = f2bf(oacc[nd][j] * inv);
        }

        __syncthreads();   // all waves done with this pass's LDS before next pass restages
    }
}

extern "C" void kernel_launch(void* const* d_in, const int* in_sizes, int n_in,
                              void* d_out, int out_size, void* d_ws, size_t ws_size,
                              hipStream_t stream) {
    const float* x     = (const float*)d_in[0];
    const float* shift = (const float*)d_in[1];
    const float* maa_x = (const float*)d_in[2];
    const float* maa_r = (const float*)d_in[3];
    const float* maa_k = (const float*)d_in[4];
    const float* maa_v = (const float*)d_in[5];
    const float* w1    = (const float*)d_in[6];
    const float* w2    = (const float*)d_in[7];
    const float* Wq    = (const float*)d_in[8];
    const float* Wk    = (const float*)d_in[9];
    const float* Wv    = (const float*)d_in[10];
    const float* Wo    = (const float*)d_in[11];
    const float* g_r   = (const float*)d_in[12];
    const float* b_r   = (const float*)d_in[13];
    const float* g_k   = (const float*)d_in[14];
    const float* b_k   = (const float*)d_in[15];
    const float* g_v   = (const float*)d_in[16];
    const float* b_v   = (const float*)d_in[17];
    const float* g_x   = (const float*)d_in[18];
    const float* b_x   = (const float*)d_in[19];
    const float* cosb  = (const float*)d_in[20];
    const float* sinb  = (const float*)d_in[21];

    char* w = (char*)d_ws;
    const size_t WB = (size_t)BT * CC * 2;     // 8 MiB bf16 plane
    u16*   wtq  = (u16*)(w + 0 * WB);
    u16*   wtk  = (u16*)(w + 1 * WB);
    u16*   wtv  = (u16*)(w + 2 * WB);
    u16*   xqb  = (u16*)(w + 3 * WB);
    u16*   xkb  = (u16*)(w + 4 * WB);
    u16*   xvb  = (u16*)(w + 5 * WB);
    u16*   qb16 = (u16*)(w + 6 * WB);
    u16*   kb16 = (u16*)(w + 7 * WB);
    u16*   vb16 = (u16*)(w + 8 * WB);
    u16*   vtb  = (u16*)(w + 9 * WB);
    float* hp   = (float*)(w + 10 * WB);                 // 6.29 MB (8 partial slices)
    float* hb   = (float*)(w + 10 * WB + 0x600000);      // 786 KB
    u16*   w1t  = (u16*)(w + 10 * WB + 0x700000);        // 384 KB
    u16*   wto  = (u16*)(w + 11 * WB);
    // aliases over consumed planes:
    u16*   qbb = (u16*)(w + 3 * WB);           // roped Q over xqb
    u16*   kbb = (u16*)(w + 4 * WB);           // roped K over xkb
    u16*   vbb = (u16*)(w + 5 * WB);           // LN'd V over xvb
    u16*   ob  = (u16*)(w + 6 * WB);           // attn out over qb16
    u16*   oln = (u16*)(w + 7 * WB);           // LN(attn) over kb16
    float* out = (float*)d_out;

    k_tconv5<<<dim3(32, 32, 5), 256, 0, stream>>>(Wq, Wk, Wv, Wo, w1,
                                                  wtq, wtk, wtv, wto, w1t);

    k_lgemm<<<dim3(BT / 16, 8), 128, 0, stream>>>(x, shift, maa_x, w1t, hp);
    k_lred<<<BT * 96 / 1024, 256, 0, stream>>>(hp, hb);
    k_mix2<<<dim3(32, 32), 256, 0, stream>>>(x, shift, hb, w2, maa_r, maa_k, maa_v,
                                             xqb, xkb, xvb);

    k_gemm_qkv<<<dim3(256, 3), 256, 0, stream>>>(xqb, xkb, xvb, wtq, wtk, wtv,
                                                 qb16, kb16, vb16);

    k_lnrope3<<<BT, 256, 0, stream>>>(qb16, kb16, vb16, qbb, kbb, vbb,
                                      g_r, b_r, g_k, b_k, g_v, b_v, cosb, sinb);
    k_vtr<<<dim3(TT / 64, HH, BB), 256, 0, stream>>>(vbb, vtb);

    k_mattn5<<<dim3(TT / 256, HH, BB), 512, 0, stream>>>(qbb, kbb, vtb, ob);

    k_ln_bb<<<BT, 256, 0, stream>>>(oln, ob, g_x, b_x);
    k_gemm1<<<256, 256, 0, stream>>>(oln, wto, out);
}

// Round 15
// 210.433 us; speedup vs baseline: 1.0860x; 1.0216x over previous
//
#include <hip/hip_runtime.h>
#include <math.h>

static constexpr int BB = 2;
static constexpr int TT = 1024;
static constexpr int CC = 2048;
static constexpr int HH = 32;
static constexpr int KD = 64;
static constexpr int BT = BB * TT;

typedef short   v8s  __attribute__((ext_vector_type(8)));
typedef float   v4f  __attribute__((ext_vector_type(4)));
typedef unsigned short u16;
typedef u16     u16x8 __attribute__((ext_vector_type(8)));
typedef u16     u16x4 __attribute__((ext_vector_type(4)));
typedef float   fx4  __attribute__((ext_vector_type(4)));

__device__ __forceinline__ u16 f2bf(float f) {
    unsigned u = __builtin_bit_cast(unsigned, f);
    u = u + 0x7FFFu + ((u >> 16) & 1u);   // RNE
    return (u16)(u >> 16);
}
__device__ __forceinline__ float bf2f(u16 v) {
    return __builtin_bit_cast(float, ((unsigned)v) << 16);
}

// async global->LDS, 16B per lane; dest is wave-uniform base + lane*16
__device__ __forceinline__ void gld16(const u16* g, u16* l) {
    __builtin_amdgcn_global_load_lds(
        (const __attribute__((address_space(1))) void*)g,
        (__attribute__((address_space(3))) void*)l, 16, 0, 0);
}

__device__ __forceinline__ void cstore(float* p, float v) { *p = v; }
__device__ __forceinline__ void cstore(u16* p, float v)   { *p = f2bf(v); }

// XCD chunk swizzle: 256 blocks -> 16x16 tile grid, each XCD a 4x8 chunk
__device__ __forceinline__ void xcd_map(int bid, int& bx, int& by) {
    int i = bid & 7;
    int j = bid >> 3;
    bx = (i & 3) * 4 + (j & 3);
    by = (i >> 2) * 8 + (j >> 2);
}

// ---------------- transpose-convert weights (z<4) + w1 (z==4) ----------------
__global__ __launch_bounds__(256) void k_tconv5(const float* __restrict__ W0,
                                                const float* __restrict__ W1,
                                                const float* __restrict__ W2,
                                                const float* __restrict__ W3,
                                                const float* __restrict__ w1,
                                                u16* __restrict__ T0, u16* __restrict__ T1,
                                                u16* __restrict__ T2, u16* __restrict__ T3,
                                                u16* __restrict__ w1t) {
    __shared__ float tile[64][97];
    int tid = threadIdx.x;
    int z = blockIdx.z;
    if (z == 4) {                              // w1 f32 [2048][96] -> bf16 [96][2048]
        if (blockIdx.y != 0) return;
        int kb = blockIdx.x * 64;
        for (int i = tid; i < 64 * 96; i += 256) {
            int r = i / 96, c = i - r * 96;
            tile[r][c] = w1[(size_t)(kb + r) * 96 + c];
        }
        __syncthreads();
        for (int i = tid; i < 96 * 64; i += 256) {
            int n = i >> 6, k = i & 63;
            w1t[(size_t)n * CC + kb + k] = f2bf(tile[k][n]);
        }
        return;
    }
    const float* W = (z == 0) ? W0 : (z == 1) ? W1 : (z == 2) ? W2 : W3;
    u16* Wt = (z == 0) ? T0 : (z == 1) ? T1 : (z == 2) ? T2 : T3;
    int nb = blockIdx.x * 64, kb = blockIdx.y * 64;
    for (int i = tid; i < 4096; i += 256) {
        int r = i >> 6, c = i & 63;
        tile[r][c] = W[(size_t)(kb + r) * CC + nb + c];
    }
    __syncthreads();
    for (int i = tid; i < 4096; i += 256) {
        int r = i >> 6, c = i & 63;
        Wt[(size_t)(nb + r) * CC + kb + c] = f2bf(tile[c][r]);
    }
}

// ---------------- K1 as MFMA GEMM, K-split x8 ----------------
__global__ __launch_bounds__(128) void k_lgemm(const float* __restrict__ x,
                                               const float* __restrict__ shift,
                                               const float* __restrict__ maa_x,
                                               const u16* __restrict__ w1t,
                                               float* __restrict__ hp) {
    __shared__ u16 As[16 * 64];
    __shared__ u16 Bs[96 * 64];
    int tid = threadIdx.x, lane = tid & 63, wave = tid >> 6;
    int brow = blockIdx.x * 16;
    int kbeg = blockIdx.y * 256;

    int ar = tid >> 3, ag = tid & 7;
    int grow = brow + ar;
    int t = grow & (TT - 1), b = grow >> 10;
    const float* xr = x + (size_t)grow * CC;
    const float* xp = (t == 0) ? (shift + (size_t)b * CC) : (xr - CC);
    u16* adst = As + ar * 64 + ((ag ^ (ar & 7)) * 8);

    v4f acc[3];
    #pragma unroll
    for (int ni = 0; ni < 3; ++ni)
        #pragma unroll
        for (int e = 0; e < 4; ++e) acc[ni][e] = 0.f;

    for (int k0 = kbeg; k0 < kbeg + 256; k0 += 64) {
        __syncthreads();
        #pragma unroll
        for (int u = 0; u < 6; ++u) {
            int r = (wave * 6 + u) * 8 + (lane >> 3);
            int sc = ((lane & 7) ^ (r & 7)) * 8;
            gld16(w1t + (size_t)r * CC + k0 + sc, Bs + (wave * 6 + u) * 512);
        }
        {
            int kb_ = k0 + ag * 8;
            fx4 x0 = *reinterpret_cast<const fx4*>(xr + kb_);
            fx4 x1 = *reinterpret_cast<const fx4*>(xr + kb_ + 4);
            fx4 p0 = *reinterpret_cast<const fx4*>(xp + kb_);
            fx4 p1 = *reinterpret_cast<const fx4*>(xp + kb_ + 4);
            fx4 m0 = *reinterpret_cast<const fx4*>(maa_x + kb_);
            fx4 m1 = *reinterpret_cast<const fx4*>(maa_x + kb_ + 4);
            fx4 r0 = x0 + (p0 - x0) * m0;
            fx4 r1 = x1 + (p1 - x1) * m1;
            u16x8 a8;
            #pragma unroll
            for (int e = 0; e < 4; ++e) { a8[e] = f2bf(r0[e]); a8[e + 4] = f2bf(r1[e]); }
            *reinterpret_cast<u16x8*>(adst) = a8;
        }
        __syncthreads();

        #pragma unroll
        for (int ks = 0; ks < 2; ++ks) {
            int kg = ks * 4 + (lane >> 4);
            int rlA = lane & 15;
            v8s af = *reinterpret_cast<const v8s*>(As + rlA * 64 + ((kg ^ (rlA & 7)) * 8));
            #pragma unroll
            for (int ni = 0; ni < 3; ++ni) {
                int rlB = wave * 48 + ni * 16 + (lane & 15);
                v8s bf = *reinterpret_cast<const v8s*>(Bs + rlB * 64 + ((kg ^ (rlB & 7)) * 8));
                acc[ni] = __builtin_amdgcn_mfma_f32_16x16x32_bf16(af, bf, acc[ni], 0, 0, 0);
            }
        }
    }

    float* hpk = hp + (size_t)blockIdx.y * BT * 96;
    #pragma unroll
    for (int ni = 0; ni < 3; ++ni) {
        int col = wave * 48 + ni * 16 + (lane & 15);
        #pragma unroll
        for (int j = 0; j < 4; ++j) {
            int row = brow + (lane >> 4) * 4 + j;
            hpk[(size_t)row * 96 + col] = acc[ni][j];
        }
    }
}

// ---------------- reduce 8 partials + tanh ----------------
__global__ __launch_bounds__(256) void k_lred(const float* __restrict__ hp,
                                              float* __restrict__ h) {
    int i = (blockIdx.x * 256 + threadIdx.x) * 4;
    const size_t S = (size_t)BT * 96;
    fx4 s = *reinterpret_cast<const fx4*>(hp + i);
    #pragma unroll
    for (int p = 1; p < 8; ++p)
        s += *reinterpret_cast<const fx4*>(hp + (size_t)p * S + i);
    fx4 o;
    #pragma unroll
    for (int e = 0; e < 4; ++e) o[e] = tanhf(s[e]);
    *reinterpret_cast<fx4*>(h + i) = o;
}

// ---------------- K2: tiled mix ----------------
__global__ __launch_bounds__(256) void k_mix2(const float* __restrict__ x,
                                              const float* __restrict__ shift,
                                              const float* __restrict__ h_in,
                                              const float* __restrict__ w2,
                                              const float* __restrict__ maa_r,
                                              const float* __restrict__ maa_k,
                                              const float* __restrict__ maa_v,
                                              u16* __restrict__ oq,
                                              u16* __restrict__ ok,
                                              u16* __restrict__ ov) {
    __shared__ float w2s[96][64];
    __shared__ float hs[64][100];
    int tid = threadIdx.x;
    int c0 = blockIdx.x * 64, r0 = blockIdx.y * 64;
    for (int i = tid; i < 96 * 64; i += 256) {
        int r = i >> 6, c = i & 63;
        w2s[r][c] = w2[(size_t)r * CC + c0 + c];
    }
    for (int i = tid; i < 64 * 96; i += 256) {
        int r = i / 96, jj = i - r * 96;
        hs[r][jj] = h_in[(size_t)(r0 + r) * 96 + jj];
    }
    __syncthreads();

    int cq = tid & 15, rg = tid >> 4;
    int c = c0 + cq * 4;
    fx4 acc[4][3];
    #pragma unroll
    for (int r = 0; r < 4; ++r)
        #pragma unroll
        for (int l = 0; l < 3; ++l)
            #pragma unroll
            for (int e = 0; e < 4; ++e) acc[r][l][e] = 0.f;

    #pragma unroll 2
    for (int i4 = 0; i4 < 8; ++i4) {
        fx4 hv[4][3];
        #pragma unroll
        for (int r = 0; r < 4; ++r) {
            int row = rg * 4 + r;
            hv[r][0] = *reinterpret_cast<const fx4*>(&hs[row][i4 * 4]);
            hv[r][1] = *reinterpret_cast<const fx4*>(&hs[row][32 + i4 * 4]);
            hv[r][2] = *reinterpret_cast<const fx4*>(&hs[row][64 + i4 * 4]);
        }
        #pragma unroll
        for (int e = 0; e < 4; ++e) {
            int i = i4 * 4 + e;
            fx4 w0 = *reinterpret_cast<const fx4*>(&w2s[i][cq * 4]);
            fx4 w1v = *reinterpret_cast<const fx4*>(&w2s[32 + i][cq * 4]);
            fx4 w2v = *reinterpret_cast<const fx4*>(&w2s[64 + i][cq * 4]);
            #pragma unroll
            for (int r = 0; r < 4; ++r) {
                acc[r][0] += hv[r][0][e] * w0;
                acc[r][1] += hv[r][1][e] * w1v;
                acc[r][2] += hv[r][2][e] * w2v;
            }
        }
    }

    fx4 m_r = *reinterpret_cast<const fx4*>(maa_r + c);
    fx4 m_k = *reinterpret_cast<const fx4*>(maa_k + c);
    fx4 m_v = *reinterpret_cast<const fx4*>(maa_v + c);
    #pragma unroll
    for (int r = 0; r < 4; ++r) {
        int grow = r0 + rg * 4 + r;
        int t = grow & (TT - 1), b = grow >> 10;
        const float* xr = x + (size_t)grow * CC;
        const float* xp = (t == 0) ? (shift + (size_t)b * CC) : (xr - CC);
        fx4 xv = *reinterpret_cast<const fx4*>(xr + c);
        fx4 pv = *reinterpret_cast<const fx4*>(xp + c);
        fx4 dx = pv - xv;
        fx4 rq = xv + dx * (m_r + acc[r][0]);
        fx4 rk = xv + dx * (m_k + acc[r][1]);
        fx4 rv = xv + dx * (m_v + acc[r][2]);
        u16x4 pq, pk, pvv;
        #pragma unroll
        for (int e = 0; e < 4; ++e) { pq[e] = f2bf(rq[e]); pk[e] = f2bf(rk[e]); pvv[e] = f2bf(rv[e]); }
        size_t o = (size_t)grow * CC + c;
        *reinterpret_cast<u16x4*>(oq + o) = pq;
        *reinterpret_cast<u16x4*>(ok + o) = pk;
        *reinterpret_cast<u16x4*>(ov + o) = pvv;
    }
}

// ---------------- MFMA bf16 GEMM body (global_load_lds staging) ----------------
template <typename CT>
__device__ __forceinline__ void gemm_body(const u16* __restrict__ A,
                                          const u16* __restrict__ Bt,
                                          CT* __restrict__ C,
                                          int bm, int bn) {
    constexpr int Kd = 2048, Nd = 2048;
    __shared__ u16 As[128 * 64];
    __shared__ u16 Bs[128 * 64];
    int tid = threadIdx.x;
    int lane = tid & 63, wave = tid >> 6;
    int wr = wave >> 1, wc = wave & 1;

    int srow[4], scol[4];
    #pragma unroll
    for (int q = 0; q < 4; ++q) {
        int e = q * 2048 + wave * 512 + lane * 8;
        int row = e >> 6;
        srow[q] = row;
        scol[q] = ((lane & 7) ^ (row & 7)) * 8;
    }

    v4f acc[4][4];
    #pragma unroll
    for (int i = 0; i < 4; ++i)
        #pragma unroll
        for (int j = 0; j < 4; ++j)
            #pragma unroll
            for (int e = 0; e < 4; ++e) acc[i][j][e] = 0.f;

    for (int k0 = 0; k0 < Kd; k0 += 64) {
        __syncthreads();
        #pragma unroll
        for (int q = 0; q < 4; ++q)
            gld16(A + (size_t)(bm + srow[q]) * Kd + k0 + scol[q], As + q * 2048 + wave * 512);
        #pragma unroll
        for (int q = 0; q < 4; ++q)
            gld16(Bt + (size_t)(bn + srow[q]) * Kd + k0 + scol[q], Bs + q * 2048 + wave * 512);
        __syncthreads();
        #pragma unroll
        for (int ks = 0; ks < 2; ++ks) {
            int kg = ks * 4 + (lane >> 4);
            v8s af[4], bf[4];
            #pragma unroll
            for (int mi = 0; mi < 4; ++mi) {
                int rl = wr * 64 + mi * 16 + (lane & 15);
                af[mi] = *reinterpret_cast<const v8s*>(As + rl * 64 + ((kg ^ (rl & 7)) * 8));
            }
            #pragma unroll
            for (int ni = 0; ni < 4; ++ni) {
                int rl = wc * 64 + ni * 16 + (lane & 15);
                bf[ni] = *reinterpret_cast<const v8s*>(Bs + rl * 64 + ((kg ^ (rl & 7)) * 8));
            }
            #pragma unroll
            for (int mi = 0; mi < 4; ++mi)
                #pragma unroll
                for (int ni = 0; ni < 4; ++ni)
                    acc[mi][ni] = __builtin_amdgcn_mfma_f32_16x16x32_bf16(af[mi], bf[ni], acc[mi][ni], 0, 0, 0);
        }
    }

    int cr = (lane >> 4) * 4;
    int ccol = lane & 15;
    #pragma unroll
    for (int mi = 0; mi < 4; ++mi)
        #pragma unroll
        for (int ni = 0; ni < 4; ++ni) {
            CT* cp = C + (size_t)(bm + wr * 64 + mi * 16 + cr) * Nd + bn + wc * 64 + ni * 16 + ccol;
            #pragma unroll
            for (int j = 0; j < 4; ++j) cstore(cp + (size_t)j * Nd, acc[mi][ni][j]);
        }
}

__global__ __launch_bounds__(256) void k_gemm_qkv(const u16* A0, const u16* A1, const u16* A2,
                                                  const u16* B0, const u16* B1, const u16* B2,
                                                  u16* C0, u16* C1, u16* C2) {
    int z = blockIdx.y;
    const u16* A = (z == 0) ? A0 : (z == 1) ? A1 : A2;
    const u16* B = (z == 0) ? B0 : (z == 1) ? B1 : B2;
    u16* C = (z == 0) ? C0 : (z == 1) ? C1 : C2;
    int bx, by;
    xcd_map(blockIdx.x, bx, by);
    gemm_body<u16>(A, B, C, by * 128, bx * 128);
}

__global__ __launch_bounds__(256) void k_gemm1(const u16* __restrict__ A,
                                               const u16* __restrict__ Bt,
                                               float* __restrict__ C) {
    int bx, by;
    xcd_map(blockIdx.x, bx, by);
    gemm_body<float>(A, Bt, C, by * 128, bx * 128);
}

// ---------------- LayerNorm (bf16 in, bf16 out) ----------------
__global__ __launch_bounds__(256) void k_ln_bb(u16* __restrict__ y, const u16* __restrict__ xin,
                                               const float* __restrict__ g, const float* __restrict__ bb) {
    int row = blockIdx.x;
    const u16* xr = xin + (size_t)row * CC;
    int tid = threadIdx.x;
    u16x8 v8 = *reinterpret_cast<const u16x8*>(xr + tid * 8);
    float xv[8];
    float s = 0.f, ss = 0.f;
    #pragma unroll
    for (int e = 0; e < 8; ++e) { xv[e] = bf2f(v8[e]); s += xv[e]; ss += xv[e] * xv[e]; }
    #pragma unroll
    for (int o = 32; o > 0; o >>= 1) { s += __shfl_xor(s, o); ss += __shfl_xor(ss, o); }
    __shared__ float red[8];
    int wid = tid >> 6;
    if ((tid & 63) == 0) { red[wid] = s; red[wid + 4] = ss; }
    __syncthreads();
    s  = red[0] + red[1] + red[2] + red[3];
    ss = red[4] + red[5] + red[6] + red[7];
    float mu  = s * (1.0f / CC);
    float var = ss * (1.0f / CC) - mu * mu;
    float rsg = rsqrtf(var + 1e-5f);
    fx4 g0 = *reinterpret_cast<const fx4*>(g + tid * 8);
    fx4 g1 = *reinterpret_cast<const fx4*>(g + tid * 8 + 4);
    fx4 b0 = *reinterpret_cast<const fx4*>(bb + tid * 8);
    fx4 b1 = *reinterpret_cast<const fx4*>(bb + tid * 8 + 4);
    u16x8 o8;
    #pragma unroll
    for (int e = 0; e < 4; ++e) o8[e]     = f2bf((xv[e] - mu) * rsg * g0[e] + b0[e]);
    #pragma unroll
    for (int e = 0; e < 4; ++e) o8[e + 4] = f2bf((xv[e + 4] - mu) * rsg * g1[e] + b1[e]);
    *reinterpret_cast<u16x8*>(y + (size_t)row * CC + tid * 8) = o8;
}

// ---------------- fused LN(q)+LN(k)+LN(v)+RoPE(q,k), bf16->bf16 (q pre-scaled 1/8) ----------------
__global__ __launch_bounds__(256) void k_lnrope3(const u16* __restrict__ qin,
                                                 const u16* __restrict__ kin,
                                                 const u16* __restrict__ vin,
                                                 u16* __restrict__ qo, u16* __restrict__ ko,
                                                 u16* __restrict__ vo,
                                                 const float* __restrict__ g_r, const float* __restrict__ b_r,
                                                 const float* __restrict__ g_k, const float* __restrict__ b_k,
                                                 const float* __restrict__ g_v, const float* __restrict__ b_v,
                                                 const float* __restrict__ cosb, const float* __restrict__ sinb) {
    int row = blockIdx.x;
    int t = row & (TT - 1);
    int tid = threadIdx.x;
    const u16* qr_ = qin + (size_t)row * CC;
    const u16* kr_ = kin + (size_t)row * CC;
    const u16* vr_ = vin + (size_t)row * CC;
    float sq = 0.f, ssq = 0.f, sk = 0.f, ssk = 0.f, sv = 0.f, ssv = 0.f;
    float xv[8];
    {
        u16x8 qv = *reinterpret_cast<const u16x8*>(qr_ + tid * 8);
        u16x8 kv = *reinterpret_cast<const u16x8*>(kr_ + tid * 8);
        u16x8 vv = *reinterpret_cast<const u16x8*>(vr_ + tid * 8);
        #pragma unroll
        for (int e = 0; e < 8; ++e) {
            float qf = bf2f(qv[e]), kf = bf2f(kv[e]);
            xv[e] = bf2f(vv[e]);
            sq += qf; ssq += qf * qf;
            sk += kf; ssk += kf * kf;
            sv += xv[e]; ssv += xv[e] * xv[e];
        }
    }
    #pragma unroll
    for (int o_ = 32; o_ > 0; o_ >>= 1) {
        sq += __shfl_xor(sq, o_); ssq += __shfl_xor(ssq, o_);
        sk += __shfl_xor(sk, o_); ssk += __shfl_xor(ssk, o_);
        sv += __shfl_xor(sv, o_); ssv += __shfl_xor(ssv, o_);
    }
    __shared__ float red[24];
    int wid = tid >> 6;
    if ((tid & 63) == 0) {
        red[wid] = sq; red[wid + 4] = ssq;
        red[wid + 8] = sk; red[wid + 12] = ssk;
        red[wid + 16] = sv; red[wid + 20] = ssv;
    }
    __syncthreads();
    sq  = red[0] + red[1] + red[2] + red[3];
    ssq = red[4] + red[5] + red[6] + red[7];
    sk  = red[8] + red[9] + red[10] + red[11];
    ssk = red[12] + red[13] + red[14] + red[15];
    sv  = red[16] + red[17] + red[18] + red[19];
    ssv = red[20] + red[21] + red[22] + red[23];
    float muq = sq * (1.0f / CC), vq = ssq * (1.0f / CC) - muq * muq, rq = rsqrtf(vq + 1e-5f);
    float muk = sk * (1.0f / CC), vk = ssk * (1.0f / CC) - muk * muk, rk = rsqrtf(vk + 1e-5f);
    float muv = sv * (1.0f / CC), vv_ = ssv * (1.0f / CC) - muv * muv, rv = rsqrtf(vv_ + 1e-5f);

    // V: straight LN, vectorized
    {
        fx4 g0 = *reinterpret_cast<const fx4*>(g_v + tid * 8);
        fx4 g1 = *reinterpret_cast<const fx4*>(g_v + tid * 8 + 4);
        fx4 b0 = *reinterpret_cast<const fx4*>(b_v + tid * 8);
        fx4 b1 = *reinterpret_cast<const fx4*>(b_v + tid * 8 + 4);
        u16x8 o8;
        #pragma unroll
        for (int e = 0; e < 4; ++e) o8[e]     = f2bf((xv[e] - muv) * rv * g0[e] + b0[e]);
        #pragma unroll
        for (int e = 0; e < 4; ++e) o8[e + 4] = f2bf((xv[e + 4] - muv) * rv * g1[e] + b1[e]);
        *reinterpret_cast<u16x8*>(vo + (size_t)row * CC + tid * 8) = o8;
    }

    // Q,K: LN + RoPE
    #pragma unroll
    for (int i = 0; i < 4; ++i) {
        int p = tid + i * 256;
        int h = p >> 5, d = p & 31;
        int c1 = h * 64 + d, c2 = c1 + 32;
        float cv = cosb[t * 32 + d], sv2 = sinb[t * 32 + d];
        float q1 = (bf2f(qr_[c1]) - muq) * rq * g_r[c1] + b_r[c1];
        float q2 = (bf2f(qr_[c2]) - muq) * rq * g_r[c2] + b_r[c2];
        qo[(size_t)row * CC + c1] = f2bf((q1 * cv - q2 * sv2) * 0.125f);
        qo[(size_t)row * CC + c2] = f2bf((q1 * sv2 + q2 * cv) * 0.125f);
        float k1 = (bf2f(kr_[c1]) - muk) * rk * g_k[c1] + b_k[c1];
        float k2 = (bf2f(kr_[c2]) - muk) * rk * g_k[c2] + b_k[c2];
        ko[(size_t)row * CC + c1] = f2bf(k1 * cv - k2 * sv2);
        ko[(size_t)row * CC + c2] = f2bf(k1 * sv2 + k2 * cv);
    }
}

// ---------------- V transpose: [b*TT+t][CC] -> [(b*HH+h)*KD+d][TT] ----------------
__global__ __launch_bounds__(256) void k_vtr(const u16* __restrict__ vin,
                                             u16* __restrict__ vout) {
    int t0 = blockIdx.x * 64, h = blockIdx.y, b = blockIdx.z;
    __shared__ u16 tile[64][72];
    int tid = threadIdx.x;
    #pragma unroll
    for (int u = 0; u < 2; ++u) {
        int g = tid + u * 256;
        int r = g >> 3, gc = g & 7;
        u16x8 vv = *reinterpret_cast<const u16x8*>(vin + (size_t)(b * TT + t0 + r) * CC + h * 64 + gc * 8);
        *reinterpret_cast<u16x8*>(&tile[r][gc * 8]) = vv;
    }
    __syncthreads();
    #pragma unroll
    for (int u = 0; u < 2; ++u) {
        int g = tid + u * 256;
        int d = g >> 3, tc = g & 7;
        u16x8 ov;
        #pragma unroll
        for (int e = 0; e < 8; ++e) ov[e] = tile[tc * 8 + e][d];
        *reinterpret_cast<u16x8*>(vout + ((size_t)(b * HH + h) * KD + d) * TT + t0 + tc * 8) = ov;
    }
}

// ---------------- MFMA bf16 flash attention: paired supertiles + fused-pair softmax ----------------
// grid (TT/256, H, B) = (4,32,2); block does st = 7-bx then st = bx (18 tiles each).
// Per barrier interval: ONE 128-key group (2 subtiles). QK^T for both subtiles first,
// then a SINGLE online-softmax update across all 128 keys (halves the serial shfl chains),
// then both PV subtiles. Same barrier/vmcnt structure as the passing round-14 kernel.
__global__ __launch_bounds__(512) void k_mattn6(const u16* __restrict__ q,
                                                const u16* __restrict__ k,
                                                const u16* __restrict__ vt,
                                                u16* __restrict__ o) {
    int h = blockIdx.y, b = blockIdx.z;
    __shared__ u16 Ks[3][2][64 * 64];
    __shared__ u16 Vs[3][2][64 * 64];
    __shared__ u16 Ps[8][2][16 * 64];
    int tid = threadIdx.x, lane = tid & 63, wave = tid >> 6;
    size_t bh = (size_t)b * TT * CC + (size_t)h * KD;
    const u16* vth = vt + (size_t)(b * HH + h) * KD * TT;
    int srow = (wave << 3) + (lane >> 3);
    int scol = ((lane & 7) ^ (srow & 7)) << 3;
    int nst2 = (int)gridDim.x * 2;             // 8 supertiles

    #pragma unroll 1
    for (int pass = 0; pass < 2; ++pass) {
        int st = (pass == 0) ? (nst2 - 1 - (int)blockIdx.x) : (int)blockIdx.x;
        int qrow0 = st * 128 + wave * 16;
        int ngrp = st + 1;                     // groups of 2 tiles

        v8s qf[2];
        {
            const u16* qp = q + bh + (size_t)(qrow0 + (lane & 15)) * CC + (lane >> 4) * 8;
            qf[0] = *reinterpret_cast<const v8s*>(qp);
            qf[1] = *reinterpret_cast<const v8s*>(qp + 32);
        }

        float mstat[4], lstat[4];
        v4f oacc[4];
        #pragma unroll
        for (int j = 0; j < 4; ++j) { mstat[j] = -1e30f; lstat[j] = 0.f; }
        #pragma unroll
        for (int nd = 0; nd < 4; ++nd)
            #pragma unroll
            for (int e = 0; e < 4; ++e) oacc[nd][e] = 0.f;

        auto STAGE2 = [&](int slot, int g) {   // stage tiles 2g, 2g+1 (4 loads/thread)
            int kt0 = 2 * g;
            gld16(k + bh + (size_t)(kt0 * 64 + srow) * CC + scol, &Ks[slot][0][wave * 512]);
            gld16(vth + (size_t)srow * TT + kt0 * 64 + scol, &Vs[slot][0][wave * 512]);
            gld16(k + bh + (size_t)((kt0 + 1) * 64 + srow) * CC + scol, &Ks[slot][1][wave * 512]);
            gld16(vth + (size_t)srow * TT + (kt0 + 1) * 64 + scol, &Vs[slot][1][wave * 512]);
        };

        STAGE2(0, 0);
        if (ngrp > 1) STAGE2(1, 1);

        for (int g = 0; g < ngrp; ++g) {
            int cur = g % 3;
            if (g + 1 < ngrp) asm volatile("s_waitcnt vmcnt(4)" ::: "memory");
            else              asm volatile("s_waitcnt vmcnt(0)" ::: "memory");
            __builtin_amdgcn_s_barrier();      // group g landed AND all waves done with g-1
            __builtin_amdgcn_sched_barrier(0);
            if (g + 2 < ngrp) STAGE2((g + 2) % 3, g + 2);   // slot freed by group g-1

            int kt0 = 2 * g;
            if (kt0 * 64 <= qrow0 + 15) {
                // ---- QK^T for BOTH subtiles (16 MFMA) ----
                v4f s[2][4];
                __builtin_amdgcn_s_setprio(1);
                #pragma unroll
                for (int sub = 0; sub < 2; ++sub) {
                    const u16* KsC = Ks[cur][sub];
                    #pragma unroll
                    for (int ni = 0; ni < 4; ++ni) {
                        #pragma unroll
                        for (int e = 0; e < 4; ++e) s[sub][ni][e] = 0.f;
                        #pragma unroll
                        for (int ks = 0; ks < 2; ++ks) {
                            int rl = ni * 16 + (lane & 15);
                            int kg = ks * 4 + (lane >> 4);
                            int swz = kg ^ (rl & 7);
                            v8s kf = *reinterpret_cast<const v8s*>(KsC + rl * 64 + swz * 8);
                            s[sub][ni] = __builtin_amdgcn_mfma_f32_16x16x32_bf16(qf[ks], kf, s[sub][ni], 0, 0, 0);
                        }
                    }
                }
                __builtin_amdgcn_s_setprio(0);

                // ---- causal mask per subtile ----
                #pragma unroll
                for (int sub = 0; sub < 2; ++sub) {
                    int kt = kt0 + sub;
                    if (kt * 64 + 63 > qrow0) {
                        int qr = qrow0 + (lane >> 4) * 4;
                        int kc = kt * 64 + (lane & 15);
                        #pragma unroll
                        for (int ni = 0; ni < 4; ++ni)
                            #pragma unroll
                            for (int j = 0; j < 4; ++j)
                                if (kc + ni * 16 > qr + j) s[sub][ni][j] = -1e30f;
                    }
                }

                // ---- SINGLE fused online softmax over 128 keys ----
                float alpha[4];
                #pragma unroll
                for (int j = 0; j < 4; ++j) {
                    float pm = fmaxf(fmaxf(s[0][0][j], s[0][1][j]), fmaxf(s[0][2][j], s[0][3][j]));
                    float pm1 = fmaxf(fmaxf(s[1][0][j], s[1][1][j]), fmaxf(s[1][2][j], s[1][3][j]));
                    pm = fmaxf(pm, pm1);
                    pm = fmaxf(pm, __shfl_xor(pm, 1));
                    pm = fmaxf(pm, __shfl_xor(pm, 2));
                    pm = fmaxf(pm, __shfl_xor(pm, 4));
                    pm = fmaxf(pm, __shfl_xor(pm, 8));
                    float mn = fmaxf(mstat[j], pm);
                    alpha[j] = __expf(mstat[j] - mn);
                    float rs = 0.f;
                    #pragma unroll
                    for (int sub = 0; sub < 2; ++sub)
                        #pragma unroll
                        for (int ni = 0; ni < 4; ++ni) {
                            float p = __expf(s[sub][ni][j] - mn);
                            s[sub][ni][j] = p;
                            rs += p;
                        }
                    rs += __shfl_xor(rs, 1);
                    rs += __shfl_xor(rs, 2);
                    rs += __shfl_xor(rs, 4);
                    rs += __shfl_xor(rs, 8);
                    lstat[j] = lstat[j] * alpha[j] + rs;
                    mstat[j] = mn;
                }
                #pragma unroll
                for (int nd = 0; nd < 4; ++nd)
                    #pragma unroll
                    for (int j = 0; j < 4; ++j) oacc[nd][j] *= alpha[j];

                // ---- P writes (both halves, wave-private) ----
                #pragma unroll
                for (int sub = 0; sub < 2; ++sub) {
                    u16* pw = Ps[wave][sub];
                    #pragma unroll
                    for (int ni = 0; ni < 4; ++ni) {
                        int kc = (lane & 15) + ni * 16;
                        #pragma unroll
                        for (int j = 0; j < 4; ++j) {
                            int qr = (lane >> 4) * 4 + j;
                            int swz = (kc >> 3) ^ (qr & 7) ^ (qr >> 3);
                            pw[qr * 64 + swz * 8 + (kc & 7)] = f2bf(s[sub][ni][j]);
                        }
                    }
                }

                // ---- P fragments + PV (both subtiles, 16 MFMA) ----
                v8s pf[2][2];
                #pragma unroll
                for (int sub = 0; sub < 2; ++sub) {
                    const u16* pw = Ps[wave][sub];
                    #pragma unroll
                    for (int ks = 0; ks < 2; ++ks) {
                        int prow = lane & 15;
                        int kg = ks * 4 + (lane >> 4);
                        int swz = kg ^ (prow & 7) ^ (prow >> 3);
                        pf[sub][ks] = *reinterpret_cast<const v8s*>(pw + prow * 64 + swz * 8);
                    }
                }
                __builtin_amdgcn_s_setprio(1);
                #pragma unroll
                for (int sub = 0; sub < 2; ++sub) {
                    const u16* VsC = Vs[cur][sub];
                    #pragma unroll
                    for (int nd = 0; nd < 4; ++nd) {
                        #pragma unroll
                        for (int ks = 0; ks < 2; ++ks) {
                            int vrow = nd * 16 + (lane & 15);
                            int vg = ks * 4 + (lane >> 4);
                            int vswz = vg ^ (vrow & 7);
                            v8s vf = *reinterpret_cast<const v8s*>(VsC + vrow * 64 + vswz * 8);
                            oacc[nd] = __builtin_amdgcn_mfma_f32_16x16x32_bf16(pf[sub][ks], vf, oacc[nd], 0, 0, 0);
                        }
                    }
                }
                __builtin_amdgcn_s_setprio(0);
            }
        }

        #pragma unroll
        for (int j = 0; j < 4; ++j) {
            int qrow = qrow0 + (lane >> 4) * 4 + j;
            float inv = 1.0f / lstat[j];
            #pragma unroll
            for (int nd = 0; nd < 4; ++nd)
                o[bh + (size_t)qrow * CC + (lane & 15) + nd * 16] = f2bf(oacc[nd][j] * inv);
        }

        __syncthreads();   // all waves done with this pass's LDS before next pass restages
    }
}

extern "C" void kernel_launch(void* const* d_in, const int* in_sizes, int n_in,
                              void* d_out, int out_size, void* d_ws, size_t ws_size,
                              hipStream_t stream) {
    const float* x     = (const float*)d_in[0];
    const float* shift = (const float*)d_in[1];
    const float* maa_x = (const float*)d_in[2];
    const float* maa_r = (const float*)d_in[3];
    const float* maa_k = (const float*)d_in[4];
    const float* maa_v = (const float*)d_in[5];
    const float* w1    = (const float*)d_in[6];
    const float* w2    = (const float*)d_in[7];
    const float* Wq    = (const float*)d_in[8];
    const float* Wk    = (const float*)d_in[9];
    const float* Wv    = (const float*)d_in[10];
    const float* Wo    = (const float*)d_in[11];
    const float* g_r   = (const float*)d_in[12];
    const float* b_r   = (const float*)d_in[13];
    const float* g_k   = (const float*)d_in[14];
    const float* b_k   = (const float*)d_in[15];
    const float* g_v   = (const float*)d_in[16];
    const float* b_v   = (const float*)d_in[17];
    const float* g_x   = (const float*)d_in[18];
    const float* b_x   = (const float*)d_in[19];
    const float* cosb  = (const float*)d_in[20];
    const float* sinb  = (const float*)d_in[21];

    char* w = (char*)d_ws;
    const size_t WB = (size_t)BT * CC * 2;     // 8 MiB bf16 plane
    u16*   wtq  = (u16*)(w + 0 * WB);
    u16*   wtk  = (u16*)(w + 1 * WB);
    u16*   wtv  = (u16*)(w + 2 * WB);
    u16*   xqb  = (u16*)(w + 3 * WB);
    u16*   xkb  = (u16*)(w + 4 * WB);
    u16*   xvb  = (u16*)(w + 5 * WB);
    u16*   qb16 = (u16*)(w + 6 * WB);
    u16*   kb16 = (u16*)(w + 7 * WB);
    u16*   vb16 = (u16*)(w + 8 * WB);
    u16*   vtb  = (u16*)(w + 9 * WB);
    float* hp   = (float*)(w + 10 * WB);                 // 6.29 MB (8 partial slices)
    float* hb   = (float*)(w + 10 * WB + 0x600000);      // 786 KB
    u16*   w1t  = (u16*)(w + 10 * WB + 0x700000);        // 384 KB
    u16*   wto  = (u16*)(w + 11 * WB);
    // aliases over consumed planes:
    u16*   qbb = (u16*)(w + 3 * WB);           // roped Q over xqb
    u16*   kbb = (u16*)(w + 4 * WB);           // roped K over xkb
    u16*   vbb = (u16*)(w + 5 * WB);           // LN'd V over xvb
    u16*   ob  = (u16*)(w + 6 * WB);           // attn out over qb16
    u16*   oln = (u16*)(w + 7 * WB);           // LN(attn) over kb16
    float* out = (float*)d_out;

    k_tconv5<<<dim3(32, 32, 5), 256, 0, stream>>>(Wq, Wk, Wv, Wo, w1,
                                                  wtq, wtk, wtv, wto, w1t);

    k_lgemm<<<dim3(BT / 16, 8), 128, 0, stream>>>(x, shift, maa_x, w1t, hp);
    k_lred<<<BT * 96 / 1024, 256, 0, stream>>>(hp, hb);
    k_mix2<<<dim3(32, 32), 256, 0, stream>>>(x, shift, hb, w2, maa_r, maa_k, maa_v,
                                             xqb, xkb, xvb);

    k_gemm_qkv<<<dim3(256, 3), 256, 0, stream>>>(xqb, xkb, xvb, wtq, wtk, wtv,
                                                 qb16, kb16, vb16);

    k_lnrope3<<<BT, 256, 0, stream>>>(qb16, kb16, vb16, qbb, kbb, vbb,
                                      g_r, b_r, g_k, b_k, g_v, b_v, cosb, sinb);
    k_vtr<<<dim3(TT / 64, HH, BB), 256, 0, stream>>>(vbb, vtb);

    k_mattn6<<<dim3(TT / 256, HH, BB), 512, 0, stream>>>(qbb, kbb, vtb, ob);

    k_ln_bb<<<BT, 256, 0, stream>>>(oln, ob, g_x, b_x);
    k_gemm1<<<256, 256, 0, stream>>>(oln, wto, out);
}